// Round 4
// baseline (5791.467 us; speedup 1.0000x reference)
//
#include <hip/hip_runtime.h>
#include <hip/hip_bf16.h>

// Problem constants (match reference)
constexpr int Bc   = 2;
constexpr int Tc   = 1024;
constexpr int Vc   = 50257;
constexpr int Lc   = 8;
constexpr int Dc   = 1024;
constexpr int Hc   = 16;
constexpr int HKVc = 4;
constexpr int HDc  = 64;     // D/H
constexpr int KVDc = 256;    // HKV*HD
constexpr int MLPc = 4096;   // 4*D
constexpr int BVc  = 65536;
constexpr int BDc  = 256;
constexpr int VEDc = 128;

constexpr int NTOK = Bc * Tc;          // 2048
constexpr long SZ_X  = (long)NTOK * Dc;    // 2,097,152
constexpr long SZ_KV = (long)NTOK * KVDc;  // 524,288
constexpr long SZ_H  = (long)NTOK * MLPc;  // 8,388,608

constexpr long W_Q  = (long)Lc * Dc * Dc;     // 8,388,608
constexpr long W_KV = (long)Lc * KVDc * Dc;   // 2,097,152
constexpr long W_FC = (long)Lc * MLPc * Dc;   // 33,554,432
constexpr long W_HD = (long)Vc * Dc;          // 51,463,168
constexpr long SZ_KVP = (long)Bc * HKVc * (Tc / 64) * 4096;  // 524,288 shorts/plane

#define NEG_BIG (-3.0e38f)

typedef __attribute__((ext_vector_type(8))) short short8;    // 8 bf16 (4 VGPRs)
typedef __attribute__((ext_vector_type(4))) short short4v;   // 4 bf16 (8 B)
typedef __attribute__((ext_vector_type(4))) float floatx4;   // 16x16 MFMA acc
typedef __attribute__((ext_vector_type(16))) float floatx16; // 32x32 MFMA acc

__device__ __forceinline__ float wave_sum(float v) {
#pragma unroll
  for (int off = 32; off >= 1; off >>= 1) v += __shfl_xor(v, off);
  return v;
}

// Bijective XCD-aware swizzle (m204 formula).
__device__ __forceinline__ void xcd_swizzle(int& bx, int& by, int nbx, int nby) {
  int n = nbx * nby;
  int lin = by * nbx + bx;
  int q = n >> 3, rm = n & 7;
  int xcd = lin & 7, idx = lin >> 3;
  int v = (xcd < rm) ? (xcd * (q + 1) + idx)
                     : (rm * (q + 1) + (xcd - rm) * q + idx);
  bx = v % nbx;
  by = v / nbx;
}

// async global->LDS, 16B per lane. LDS dest = wave-uniform base + lane*16.
__device__ __forceinline__ void gll16(const void* g, void* l) {
  __builtin_amdgcn_global_load_lds(
      (const __attribute__((address_space(1))) unsigned int*)g,
      (__attribute__((address_space(3))) unsigned int*)l, 16, 0, 0);
}

// ---------------------------------------------------------------------------
// bf16 split helpers: f = bf2f(hi) + bf2f(lo) + O(2^-17 * f)
// ---------------------------------------------------------------------------
__device__ __forceinline__ short f2bf(float f) {
  unsigned u = __float_as_uint(f);
  return (short)((u + 0x7fffu + ((u >> 16) & 1u)) >> 16);
}
__device__ __forceinline__ float bf2f(short h) {
  return __uint_as_float(((unsigned)(unsigned short)h) << 16);
}

// ---------------------------------------------------------------------------
// Weight conversion: fp32 -> (hi, lo) bf16 planes. 8 elems/thread.
// ---------------------------------------------------------------------------
__global__ __launch_bounds__(256) void wcvt_kernel(
    const float* __restrict__ src, short* __restrict__ hi,
    short* __restrict__ lo, long n8) {
  long i = (long)blockIdx.x * 256 + threadIdx.x;
  if (i >= n8) return;
  const float* s = src + i * 8;
  float4 f0 = *(const float4*)s;
  float4 f1 = *(const float4*)(s + 4);
  float fv[8] = {f0.x, f0.y, f0.z, f0.w, f1.x, f1.y, f1.z, f1.w};
  short8 h8, l8;
#pragma unroll
  for (int e = 0; e < 8; ++e) {
    short hb = f2bf(fv[e]);
    h8[e] = hb;
    l8[e] = f2bf(fv[e] - bf2f(hb));
  }
  *(short8*)(hi + i * 8) = h8;
  *(short8*)(lo + i * 8) = l8;
}

// ---------------------------------------------------------------------------
// Embedding (unchanged)
// ---------------------------------------------------------------------------
__global__ __launch_bounds__(256) void embed_kernel(
    const int* __restrict__ ids, const float* __restrict__ embed_w,
    const float* __restrict__ big_w, const float* __restrict__ big_proj,
    const float* __restrict__ big_scale, const float* __restrict__ ve_w,
    const float* __restrict__ ve_proj, const float* __restrict__ ve_scale,
    float* __restrict__ raw_x, float* __restrict__ vemb) {
  int bt = blockIdx.x;
  int tid = threadIdx.x;
  int t = bt % Tc;
  int tok = ids[bt];

  const float* e = embed_w + (size_t)tok * Dc;
  float ev[4];
  float ss = 0.f;
#pragma unroll
  for (int i = 0; i < 4; ++i) {
    ev[i] = e[tid + i * 256];
    ss += ev[i] * ev[i];
  }
  __shared__ float red[4];
  __shared__ float brow[BDc];
  __shared__ float verow[VEDc];
  float wsum = wave_sum(ss);
  if ((tid & 63) == 0) red[tid >> 6] = wsum;

  int bg;
  if (t == 0) {
    bg = BVc - 1;
  } else {
    unsigned a = (unsigned)ids[bt];
    unsigned p = (unsigned)ids[bt - 1];
    bg = (int)(((36313u * a) ^ (27191u * p)) % 65535u);
  }
  brow[tid] = big_w[(size_t)bg * BDc + tid];
  if (tid < VEDc) verow[tid] = ve_w[(size_t)tok * VEDc + tid];
  __syncthreads();

  float tot = red[0] + red[1] + red[2] + red[3];
  float rn = rsqrtf(tot / (float)Dc + 1e-6f);
  float bs = big_scale[0];
#pragma unroll
  for (int i = 0; i < 4; ++i) {
    int d = tid + i * 256;
    const float* bp = big_proj + (size_t)d * BDc;
    float dot = 0.f;
    for (int c = 0; c < BDc; ++c) dot += brow[c] * bp[c];
    raw_x[(size_t)bt * Dc + d] = ev[i] * rn + dot * bs;
  }
  {
    float vs = ve_scale[0];
    int d = tid;
    const float* vp = ve_proj + (size_t)d * VEDc;
    float dot = 0.f;
    for (int c = 0; c < VEDc; ++c) dot += verow[c] * vp[c];
    vemb[(size_t)bt * KVDc + d] = dot * vs;
  }
}

// ---------------------------------------------------------------------------
// Smear (unchanged)
// ---------------------------------------------------------------------------
__global__ __launch_bounds__(256) void smear_kernel(
    const float* __restrict__ raw, const float* __restrict__ gate,
    float* __restrict__ x, float* __restrict__ x0) {
  long idx = (long)blockIdx.x * 256 + threadIdx.x;
  if (idx >= SZ_X) return;
  int d = (int)(idx & (Dc - 1));
  int t = (int)((idx / Dc) & (Tc - 1));
  float g = 1.f / (1.f + expf(-gate[d]));
  float cur = raw[idx];
  float prev = (t > 0) ? raw[idx - Dc] : 0.f;
  float val = (1.f - g) * cur + g * prev;
  x[idx] = val;
  x0[idx] = val;
}

// ---------------------------------------------------------------------------
// Pre-layer: x_in = mix0*x + mix1*x0 ; xn planes = split(rms(x_in)).
// ---------------------------------------------------------------------------
__global__ __launch_bounds__(256) void prelayer_kernel(
    const float* __restrict__ x, const float* __restrict__ x0,
    const float* __restrict__ mix, float* __restrict__ x_in,
    short* __restrict__ xnh, short* __restrict__ xnl) {
  int bt = blockIdx.x;
  int tid = threadIdx.x;
  const float* xr = x + (size_t)bt * Dc;
  const float* x0r = x0 + (size_t)bt * Dc;
  float vals[4];
  float ss = 0.f;
#pragma unroll
  for (int i = 0; i < 4; ++i) {
    int d = tid + i * 256;
    float v = mix[d] * xr[d] + mix[Dc + d] * x0r[d];
    vals[i] = v;
    ss += v * v;
  }
  __shared__ float red[4];
  float wsum = wave_sum(ss);
  if ((tid & 63) == 0) red[tid >> 6] = wsum;
  __syncthreads();
  float tot = red[0] + red[1] + red[2] + red[3];
  float rn = rsqrtf(tot / (float)Dc + 1e-6f);
#pragma unroll
  for (int i = 0; i < 4; ++i) {
    int d = tid + i * 256;
    size_t idx = (size_t)bt * Dc + d;
    x_in[idx] = vals[i];
    float vn = vals[i] * rn;
    short hb = f2bf(vn);
    xnh[idx] = hb;
    xnl[idx] = f2bf(vn - bf2f(hb));
  }
}

// ---------------------------------------------------------------------------
// RMS over D -> bf16 hi/lo planes. Block per token.
// ---------------------------------------------------------------------------
__global__ __launch_bounds__(256) void rms_split_kernel(
    const float* __restrict__ in, short* __restrict__ oh,
    short* __restrict__ ol) {
  int bt = blockIdx.x;
  int tid = threadIdx.x;
  const float* p = in + (size_t)bt * Dc;
  float v[4];
  float ss = 0.f;
#pragma unroll
  for (int i = 0; i < 4; ++i) {
    v[i] = p[tid + i * 256];
    ss += v[i] * v[i];
  }
  __shared__ float red[4];
  float wsum = wave_sum(ss);
  if ((tid & 63) == 0) red[tid >> 6] = wsum;
  __syncthreads();
  float tot = red[0] + red[1] + red[2] + red[3];
  float rn = rsqrtf(tot / (float)Dc + 1e-6f);
#pragma unroll
  for (int i = 0; i < 4; ++i) {
    size_t idx = (size_t)bt * Dc + tid + i * 256;
    float vn = v[i] * rn;
    short hb = f2bf(vn);
    oh[idx] = hb;
    ol[idx] = f2bf(vn - bf2f(hb));
  }
}

// ---------------------------------------------------------------------------
// Double-buffered plane GEMM body (bf16x2 split, 32x32x16 MFMA):
//   C[M,N] = epi( A[M,K] @ W[N,K].T ),  A/W as bf16 hi/lo planes.
// Tile BM x 128, BK=32, 4 waves (2x2), wave tile (BM/2) x 64, 32x32 frags.
// LDS frag order: subtile (rg,ks) = 32 rows x 16 k at (rg*2+ks)*1024B,
// lane l -> l*16B (row l&31, k-octet l>>5) => conflict-free, zero cvt.
// T3-min schedule: prefetch k0+32 into buf^1 BEFORE compute; ONE barrier/step.
// ---------------------------------------------------------------------------
template <int BM>
__device__ __forceinline__ void gemm_db_body(
    const short* __restrict__ Ah, const short* __restrict__ Al,
    const short* __restrict__ Bh, const short* __restrict__ Bl,
    float* __restrict__ C, short* __restrict__ Ch, short* __restrict__ Cl,
    const float* __restrict__ base, const float* __restrict__ colscale,
    int m0, int n0, int N, int ldc, int K, int act, short* lds) {
  constexpr int RGA = BM / 32;            // A rowgroups
  constexpr int RGB = 4;                  // B rowgroups (BN=128)
  constexpr int NSTG = (RGA + RGB) * 4;   // subtile stages (2 ks x 2 planes)
  constexpr int SPW = NSTG / 4;           // stages per wave
  constexpr int PLA = RGA * 1024;         // shorts per A plane per buffer
  constexpr int PLB = RGB * 1024;
  constexpr int HB = 2 * (PLA + PLB);     // shorts per buffer
  constexpr int FI = BM / 64;             // A frags per wave (1 or 2)

  int tid = threadIdx.x, lane = tid & 63, wv = tid >> 6;

  // per-wave stage list: s = wv*SPW + t
  const short* gsrc[SPW];
  int ldst[SPW];
#pragma unroll
  for (int t = 0; t < SPW; ++t) {
    int s = wv * SPW + t;
    int rg, ks, poff;
    const short* plane;
    if (s < RGA * 4) {
      int p = s / (RGA * 2);
      int rem = s % (RGA * 2);
      rg = rem >> 1; ks = rem & 1;
      plane = p ? Al : Ah;
      poff = p ? PLA : 0;
      int row = m0 + rg * 32 + (lane & 31);
      gsrc[t] = plane + (size_t)row * K + ks * 16 + (lane >> 5) * 8;
    } else {
      int s2 = s - RGA * 4;
      int p = s2 / (RGB * 2);
      int rem = s2 % (RGB * 2);
      rg = rem >> 1; ks = rem & 1;
      plane = p ? Bl : Bh;
      poff = 2 * PLA + (p ? PLB : 0);
      int row = n0 + rg * 32 + (lane & 31);
      if (row >= N) row = N - 1;  // tail clamp (head GEMM)
      gsrc[t] = plane + (size_t)row * K + ks * 16 + (lane >> 5) * 8;
    }
    ldst[t] = poff + (rg * 2 + ks) * 512;
  }

  int wm = (wv >> 1) * (BM / 2), wn = (wv & 1) * 64;
  floatx16 acc[FI][2] = {};

  // prologue: stage k0=0 into buffer 0
#pragma unroll
  for (int t = 0; t < SPW; ++t) gll16(gsrc[t], lds + ldst[t]);
#pragma unroll
  for (int t = 0; t < SPW; ++t) gsrc[t] += 32;
  __syncthreads();

  int cur = 0;
  for (int k0 = 0; k0 < K; k0 += 32) {
    if (k0 + 32 < K) {
      int nb = (cur ^ 1) * HB;
#pragma unroll
      for (int t = 0; t < SPW; ++t) gll16(gsrc[t], lds + nb + ldst[t]);
#pragma unroll
      for (int t = 0; t < SPW; ++t) gsrc[t] += 32;
    }
    const short* As_h = lds + cur * HB;
    const short* As_l = As_h + PLA;
    const short* Bs_h = As_h + 2 * PLA;
    const short* Bs_l = Bs_h + PLB;
#pragma unroll
    for (int ks = 0; ks < 2; ++ks) {
      short8 ah[FI], al2[FI], bh[2], bl2[2];
#pragma unroll
      for (int i = 0; i < FI; ++i) {
        int rg = (wm >> 5) + i;
        ah[i]  = *(const short8*)(As_h + (rg * 2 + ks) * 512 + lane * 8);
        al2[i] = *(const short8*)(As_l + (rg * 2 + ks) * 512 + lane * 8);
      }
#pragma unroll
      for (int j = 0; j < 2; ++j) {
        int rg = (wn >> 5) + j;
        bh[j]  = *(const short8*)(Bs_h + (rg * 2 + ks) * 512 + lane * 8);
        bl2[j] = *(const short8*)(Bs_l + (rg * 2 + ks) * 512 + lane * 8);
      }
#pragma unroll
      for (int i = 0; i < FI; ++i)
#pragma unroll
        for (int j = 0; j < 2; ++j) {
          acc[i][j] = __builtin_amdgcn_mfma_f32_32x32x16_bf16(ah[i], bh[j], acc[i][j], 0, 0, 0);
          acc[i][j] = __builtin_amdgcn_mfma_f32_32x32x16_bf16(ah[i], bl2[j], acc[i][j], 0, 0, 0);
          acc[i][j] = __builtin_amdgcn_mfma_f32_32x32x16_bf16(al2[i], bh[j], acc[i][j], 0, 0, 0);
        }
    }
    __syncthreads();  // drains vmcnt: prefetch (issued before compute) lands
    cur ^= 1;
  }

  // epilogue: 32x32 C/D layout col=lane&31, row=(r&3)+8*(r>>2)+4*(lane>>5)
  int cl = lane & 31, g2 = lane >> 5;
#pragma unroll
  for (int i = 0; i < FI; ++i) {
#pragma unroll
    for (int j = 0; j < 2; ++j) {
      int col = n0 + wn + 32 * j + cl;
      if (col >= N) continue;
      floatx16 f = acc[i][j];
#pragma unroll
      for (int r = 0; r < 16; ++r) {
        int row = m0 + wm + 32 * i + (r & 3) + 8 * (r >> 2) + 4 * g2;
        float v = f[r];
        if (act == 1) {
          float hx = (v >= 0.f) ? v : 0.5f * v;
          v = hx * hx;
        }
        if (colscale) v *= colscale[col];
        size_t idx = (size_t)row * ldc + col;
        if (base) v += base[idx];
        if (Ch) {
          short hb = f2bf(v);
          Ch[idx] = hb;
          Cl[idx] = f2bf(v - bf2f(hb));
        } else {
          C[idx] = v;
        }
      }
    }
  }
}

__global__ __launch_bounds__(256) void gemm_db128(
    const short* __restrict__ Ah, const short* __restrict__ Al,
    const short* __restrict__ Bh, const short* __restrict__ Bl,
    float* __restrict__ C, short* __restrict__ Ch, short* __restrict__ Cl,
    const float* __restrict__ base, const float* __restrict__ colscale, int N,
    int K, int act) {
  __shared__ short lds[32768];  // 64 KiB: 2 buffers x (A 8KB x2 + B 8KB x2)
  int bx = blockIdx.x, by = blockIdx.y;
  xcd_swizzle(bx, by, gridDim.x, gridDim.y);
  gemm_db_body<128>(Ah, Al, Bh, Bl, C, Ch, Cl, base, colscale, bx * 128,
                    by * 128, N, N, K, act, lds);
}

__global__ __launch_bounds__(256) void gemm_db64(
    const short* __restrict__ Ah, const short* __restrict__ Al,
    const short* __restrict__ Bh, const short* __restrict__ Bl,
    float* __restrict__ C, const float* __restrict__ base,
    const float* __restrict__ colscale, int N, int K, int act) {
  __shared__ short lds[24576];  // 48 KiB
  int bx = blockIdx.x, by = blockIdx.y;
  xcd_swizzle(bx, by, gridDim.x, gridDim.y);
  gemm_db_body<64>(Ah, Al, Bh, Bl, C, nullptr, nullptr, base, colscale,
                   bx * 64, by * 128, N, N, K, act, lds);
}

// Fused q,k,v projection: grid (NTOK/64, 12). by<8 -> q, 8-9 -> k, 10-11 -> v.
__global__ __launch_bounds__(256) void qkv_db(
    const short* __restrict__ xnh, const short* __restrict__ xnl,
    const short* __restrict__ wqh, const short* __restrict__ wql,
    const short* __restrict__ wkh, const short* __restrict__ wkl,
    const short* __restrict__ wvh, const short* __restrict__ wvl,
    float* __restrict__ qb, float* __restrict__ kb, float* __restrict__ vb,
    const float* __restrict__ vemb, int K) {
  __shared__ short lds[24576];
  int bx = blockIdx.x, by = blockIdx.y;
  xcd_swizzle(bx, by, gridDim.x, gridDim.y);
  const short *Bh, *Bl;
  float* C;
  const float* base = nullptr;
  int n0, ldn;
  if (by < 8) {
    Bh = wqh; Bl = wql; C = qb; n0 = by * 128; ldn = Dc;
  } else if (by < 10) {
    Bh = wkh; Bl = wkl; C = kb; n0 = (by - 8) * 128; ldn = KVDc;
  } else {
    Bh = wvh; Bl = wvl; C = vb; base = vemb; n0 = (by - 10) * 128; ldn = KVDc;
  }
  gemm_db_body<64>(xnh, xnl, Bh, Bl, C, nullptr, nullptr, base, nullptr,
                   bx * 64, n0, ldn, ldn, K, 0, lds);
}

// ---------------------------------------------------------------------------
// QK head-RMS + RoPE (+q_gain). Block per token. (unchanged)
// ---------------------------------------------------------------------------
__global__ __launch_bounds__(256) void qkrope_kernel(
    float* __restrict__ q, float* __restrict__ k,
    const float* __restrict__ q_gain) {
  int bt = blockIdx.x;
  int t = bt % Tc;
  int tid = threadIdx.x;
  int lane = tid & 63, wv = tid >> 6;
  int fi = lane & 31;
  float inv = expf(-(float)(2 * fi) * (9.210340372f / 64.f));
  float ang = (float)t * inv;
  float cv = cosf(ang);
  float sv = sinf(ang);

#pragma unroll
  for (int hh = 0; hh < 4; ++hh) {
    int h = wv + hh * 4;
    float* qp = q + (size_t)bt * Dc + h * 64;
    float val = qp[lane];
    float ss = wave_sum(val * val);
    float rn = rsqrtf(ss / 64.f + 1e-6f);
    val *= rn;
    float partner = __shfl(val, lane ^ 32);
    float out = (lane < 32) ? (val * cv + partner * sv) : (val * cv - partner * sv);
    out *= q_gain[h];
    qp[lane] = out;
  }
  {
    int h = wv;
    float* kp = k + (size_t)bt * KVDc + h * 64;
    float val = kp[lane];
    float ss = wave_sum(val * val);
    float rn = rsqrtf(ss / 64.f + 1e-6f);
    val *= rn;
    float partner = __shfl(val, lane ^ 32);
    float out = (lane < 32) ? (val * cv + partner * sv) : (val * cv - partner * sv);
    kp[lane] = out;
  }
}

// ---------------------------------------------------------------------------
// K/V^T frag-order plane prep. Grid (Tc/64, Bc*HKVc). One 64x64 tile each.
// K planes: subtile s=half*4+rg, pos p: row rg*16+(p&15), d half*32+(p>>4)*8+e
// Vt planes: subtile s=ks*4+jd,  pos p: d jd*16+(p&15),  k ks*32+(p>>4)*8+e
// ---------------------------------------------------------------------------
__global__ __launch_bounds__(256) void kvprep_kernel(
    const float* __restrict__ kb, const float* __restrict__ vb,
    short* __restrict__ khG, short* __restrict__ klG,
    short* __restrict__ vthG, short* __restrict__ vtlG) {
  __shared__ float kf[64][65];
  __shared__ float vf[64][65];
  int kt = blockIdx.x, bh = blockIdx.y;
  int b = bh >> 2, hkv = bh & 3;
  int tid = threadIdx.x;
#pragma unroll
  for (int u = 0; u < 4; ++u) {
    int idx = tid + u * 256;  // 0..1023 float4 units
    int row = idx >> 4, c4 = idx & 15;
    size_t off = ((size_t)(b * Tc + kt * 64 + row)) * KVDc + hkv * 64 + c4 * 4;
    float4 k4 = *(const float4*)(kb + off);
    float4 v4 = *(const float4*)(vb + off);
    kf[row][c4 * 4 + 0] = k4.x; kf[row][c4 * 4 + 1] = k4.y;
    kf[row][c4 * 4 + 2] = k4.z; kf[row][c4 * 4 + 3] = k4.w;
    vf[row][c4 * 4 + 0] = v4.x; vf[row][c4 * 4 + 1] = v4.y;
    vf[row][c4 * 4 + 2] = v4.z; vf[row][c4 * 4 + 3] = v4.w;
  }
  __syncthreads();
  size_t gb = ((size_t)(bh * (Tc / 64) + kt)) * 4096;
#pragma unroll
  for (int u = 0; u < 2; ++u) {
    int unit = tid + u * 256;  // 0..511
    int s = unit >> 6, p = unit & 63;
    {  // K plane
      int half = s >> 2, rg = s & 3;
      int row = rg * 16 + (p & 15);
      int d0 = half * 32 + (p >> 4) * 8;
      short8 h8, l8;
#pragma unroll
      for (int e = 0; e < 8; ++e) {
        float v = kf[row][d0 + e];
        short hb = f2bf(v);
        h8[e] = hb;
        l8[e] = f2bf(v - bf2f(hb));
      }
      *(short8*)(khG + gb + s * 512 + p * 8) = h8;
      *(short8*)(klG + gb + s * 512 + p * 8) = l8;
    }
    {  // V^T plane
      int ks = s >> 2, jd = s & 3;
      int d = jd * 16 + (p & 15);
      int k0 = ks * 32 + (p >> 4) * 8;
      short8 h8, l8;
#pragma unroll
      for (int e = 0; e < 8; ++e) {
        float v = vf[k0 + e][d];
        short hb = f2bf(v);
        h8[e] = hb;
        l8[e] = f2bf(v - bf2f(hb));
      }
      *(short8*)(vthG + gb + s * 512 + p * 8) = h8;
      *(short8*)(vtlG + gb + s * 512 + p * 8) = l8;
    }
  }
}

// ---------------------------------------------------------------------------
// MFMA causal GQA flash attention + v-direction-removal epilogue.
// K/V^T staged from pre-built frag-order planes via global_load_lds.
// ---------------------------------------------------------------------------
__global__ __launch_bounds__(256) void attn_mfma(
    const float* __restrict__ qg_, const float* __restrict__ vg_,
    const short* __restrict__ khG, const short* __restrict__ klG,
    const short* __restrict__ vthG, const short* __restrict__ vtlG,
    short* __restrict__ yh_, short* __restrict__ yl_) {
  __shared__ short smem[32768];  // 64 KiB
  short* Khi  = smem;
  short* Klo  = smem + 4096;
  short* Vthi = smem + 8192;
  short* Vtlo = smem + 12288;

  int qt = blockIdx.x;
  int bh = blockIdx.y;
  int b = bh >> 2, hkv = bh & 3;
  int tid = threadIdx.x;
  int lane = tid & 63, wv = tid >> 6;
  int x = lane & 15, g = lane >> 4;
  int h = hkv * 4 + wv;
  int qbase = qt * 32;

  short* PAhi = smem + 16384 + wv * 2048;
  short* PAlo = smem + 24576 + wv * 2048;

  short8 qh[2][2], qlo[2][2];
#pragma unroll
  for (int j = 0; j < 2; ++j)
#pragma unroll
    for (int ks = 0; ks < 2; ++ks) {
      int qrow = qbase + 16 * j + x;
      const float* qp =
          qg_ + ((size_t)(b * Tc + qrow)) * Dc + h * 64 + ks * 32 + g * 8;
      float4 f0 = *(const float4*)qp;
      float4 f1 = *(const float4*)(qp + 4);
      float fv[8] = {f0.x, f0.y, f0.z, f0.w, f1.x, f1.y, f1.z, f1.w};
#pragma unroll
      for (int e = 0; e < 8; ++e) {
        short hb = f2bf(fv[e]);
        qh[j][ks][e] = hb;
        qlo[j][ks][e] = f2bf(fv[e] - bf2f(hb));
      }
    }

  // per-wave staging source (wave wv stages plane wv: Khi/Klo/Vthi/Vtlo)
  const short* planes[4] = {khG, klG, vthG, vtlG};
  const short* gplane = planes[wv] + ((size_t)bh * (Tc / 64)) * 4096 + lane * 8;
  short* lplane = smem + wv * 4096;

  floatx4 o[2][4] = {};
  float m_run[2] = {NEG_BIG, NEG_BIG};
  float l_run[2] = {0.f, 0.f};

  int nkt = (qbase >> 6) + 1;
  for (int kt = 0; kt < nkt; ++kt) {
    const short* gs = gplane + (size_t)kt * 4096;
#pragma unroll
    for (int t = 0; t < 8; ++t) gll16(gs + t * 512, lplane + t * 512);
    __syncthreads();

    floatx4 st[4][2] = {};
#pragma unroll
    for (int ks = 0; ks < 2; ++ks) {
#pragma unroll
      for (int i = 0; i < 4; ++i) {
        short8 ka_h = *(const short8*)(Khi + ks * 2048 + i * 512 + lane * 8);
        short8 ka_l = *(const short8*)(Klo + ks * 2048 + i * 512 + lane * 8);
#pragma unroll
        for (int j = 0; j < 2; ++j) {
          st[i][j] = __builtin_amdgcn_mfma_f32_16x16x32_bf16(ka_h, qh[j][ks], st[i][j], 0, 0, 0);
          st[i][j] = __builtin_amdgcn_mfma_f32_16x16x32_bf16(ka_h, qlo[j][ks], st[i][j], 0, 0, 0);
          st[i][j] = __builtin_amdgcn_mfma_f32_16x16x32_bf16(ka_l, qh[j][ks], st[i][j], 0, 0, 0);
        }
      }
    }

    float al[2];
#pragma unroll
    for (int j = 0; j < 2; ++j) {
      int qrow = qbase + 16 * j + x;
      float mx = NEG_BIG;
#pragma unroll
      for (int i = 0; i < 4; ++i) {
#pragma unroll
        for (int r = 0; r < 4; ++r) {
          int krow = kt * 64 + 16 * i + 4 * g + r;
          float s = st[i][j][r] * 0.125f;
          if (krow > qrow) s = NEG_BIG;
          st[i][j][r] = s;
          mx = fmaxf(mx, s);
        }
      }
      mx = fmaxf(mx, __shfl_xor(mx, 16));
      mx = fmaxf(mx, __shfl_xor(mx, 32));
      float m_new = fmaxf(m_run[j], mx);
      al[j] = __expf(m_run[j] - m_new);
      float ts = 0.f;
#pragma unroll
      for (int i = 0; i < 4; ++i) {
#pragma unroll
        for (int r = 0; r < 4; ++r) {
          float p = __expf(st[i][j][r] - m_new);
          st[i][j][r] = p;
          ts += p;
        }
      }
      ts += __shfl_xor(ts, 16);
      ts += __shfl_xor(ts, 32);
      l_run[j] = l_run[j] * al[j] + ts;
      m_run[j] = m_new;
    }

#pragma unroll
    for (int j = 0; j < 2; ++j) {
#pragma unroll
      for (int i = 0; i < 4; ++i) {
        short4v h4, l4;
#pragma unroll
        for (int r = 0; r < 4; ++r) {
          float p = st[i][j][r];
          short hb = f2bf(p);
          h4[r] = hb;
          l4[r] = f2bf(p - bf2f(hb));
        }
        int offp = (i >> 1) * 1024 + j * 512 +
                   (x + (2 * (i & 1) + (g >> 1)) * 16) * 8 + 4 * (g & 1);
        *(short4v*)(PAhi + offp) = h4;
        *(short4v*)(PAlo + offp) = l4;
      }
    }

#pragma unroll
    for (int iO = 0; iO < 2; ++iO) {
#pragma unroll
      for (int r = 0; r < 4; ++r) {
        float a = __shfl(al[iO], 4 * g + r);
#pragma unroll
        for (int jd = 0; jd < 4; ++jd) o[iO][jd][r] *= a;
      }
    }
    __syncthreads();

#pragma unroll
    for (int ks = 0; ks < 2; ++ks) {
      short8 pa_h[2], pa_l[2];
#pragma unroll
      for (int iO = 0; iO < 2; ++iO) {
        pa_h[iO] = *(const short8*)(PAhi + ks * 1024 + iO * 512 + lane * 8);
        pa_l[iO] = *(const short8*)(PAlo + ks * 1024 + iO * 512 + lane * 8);
      }
#pragma unroll
      for (int jd = 0; jd < 4; ++jd) {
        short8 vb_h = *(const short8*)(Vthi + ks * 2048 + jd * 512 + lane * 8);
        short8 vb_l = *(const short8*)(Vtlo + ks * 2048 + jd * 512 + lane * 8);
#pragma unroll
        for (int iO = 0; iO < 2; ++iO) {
          o[iO][jd] = __builtin_amdgcn_mfma_f32_16x16x32_bf16(pa_h[iO], vb_h, o[iO][jd], 0, 0, 0);
          o[iO][jd] = __builtin_amdgcn_mfma_f32_16x16x32_bf16(pa_h[iO], vb_l, o[iO][jd], 0, 0, 0);
          o[iO][jd] = __builtin_amdgcn_mfma_f32_16x16x32_bf16(pa_l[iO], vb_h, o[iO][jd], 0, 0, 0);
        }
      }
    }
    __syncthreads();
  }

#pragma unroll
  for (int iO = 0; iO < 2; ++iO) {
#pragma unroll
    for (int r = 0; r < 4; ++r) {
      float lr = __shfl(l_run[iO], 4 * g + r);
      float rcp = 1.f / lr;
      int qrow = qbase + 16 * iO + 4 * g + r;
      const float* vr = vg_ + ((size_t)(b * Tc + qrow)) * KVDc + hkv * 64;
      float vv[4], oo[4];
      float pn = 0.f, pd = 0.f;
#pragma unroll
      for (int jd = 0; jd < 4; ++jd) {
        vv[jd] = vr[16 * jd + x];
        oo[jd] = o[iO][jd][r] * rcp;
        pn += vv[jd] * vv[jd];
        pd += oo[jd] * vv[jd];
      }
#pragma unroll
      for (int off = 1; off <= 8; off <<= 1) {
        pn += __shfl_xor(pn, off);
        pd += __shfl_xor(pd, off);
      }
      float nrm = sqrtf(pn);
      float mxv = fmaxf(nrm, 1e-12f);
      float si = 1.f / mxv;
      float co = pd * si * si;
      size_t ybase = ((size_t)(b * Tc + qrow)) * Dc + h * 64;
#pragma unroll
      for (int jd = 0; jd < 4; ++jd) {
        float val = oo[jd] - co * vv[jd];
        short hb = f2bf(val);
        yh_[ybase + 16 * jd + x] = hb;
        yl_[ybase + 16 * jd + x] = f2bf(val - bf2f(hb));
      }
    }
  }
}

// ---------------------------------------------------------------------------
extern "C" void kernel_launch(void* const* d_in, const int* in_sizes, int n_in,
                              void* d_out, int out_size, void* d_ws,
                              size_t ws_size, hipStream_t stream) {
  const int* ids          = (const int*)d_in[0];
  const float* embed_w    = (const float*)d_in[1];
  const float* big_w      = (const float*)d_in[2];
  const float* big_proj   = (const float*)d_in[3];
  const float* big_scale  = (const float*)d_in[4];
  const float* smear_gate = (const float*)d_in[5];
  const float* ve_w       = (const float*)d_in[6];
  const float* ve_proj    = (const float*)d_in[7];
  const float* ve_scale   = (const float*)d_in[8];
  const float* Wq         = (const float*)d_in[9];
  const float* Wk         = (const float*)d_in[10];
  const float* Wv         = (const float*)d_in[11];
  const float* Wo         = (const float*)d_in[12];
  const float* q_gain     = (const float*)d_in[13];
  const float* attn_scale = (const float*)d_in[14];
  const float* mlp_scale  = (const float*)d_in[15];
  const float* resid_mix  = (const float*)d_in[16];
  const float* Wfc        = (const float*)d_in[17];
  const float* Wp         = (const float*)d_in[18];
  const float* head_w     = (const float*)d_in[19];
  float* out = (float*)d_out;

  // ---- workspace layout ----
  char* p = (char*)d_ws;
  float* x     = (float*)p; p += SZ_X * 4;
  float* x0    = (float*)p; p += SZ_X * 4;
  float* x_in  = (float*)p; p += SZ_X * 4;
  float* qb    = (float*)p; p += SZ_X * 4;
  float* kb    = (float*)p; p += SZ_KV * 4;
  float* vb    = (float*)p; p += SZ_KV * 4;
  float* vemb  = (float*)p; p += SZ_KV * 4;
  float* raw_x = (float*)p; p += SZ_X * 4;
  short* xnh = (short*)p; p += SZ_X * 2;
  short* xnl = (short*)p; p += SZ_X * 2;
  short* yh  = (short*)p; p += SZ_X * 2;
  short* yl  = (short*)p; p += SZ_X * 2;
  short* hh  = (short*)p; p += SZ_H * 2;
  short* hl  = (short*)p; p += SZ_H * 2;
  short* khG  = (short*)p; p += SZ_KVP * 2;
  short* klG  = (short*)p; p += SZ_KVP * 2;
  short* vthG = (short*)p; p += SZ_KVP * 2;
  short* vtlG = (short*)p; p += SZ_KVP * 2;
  short* wqh = (short*)p; p += W_Q * 2;
  short* wql = (short*)p; p += W_Q * 2;
  short* wkh = (short*)p; p += W_KV * 2;
  short* wkl = (short*)p; p += W_KV * 2;
  short* wvh = (short*)p; p += W_KV * 2;
  short* wvl = (short*)p; p += W_KV * 2;
  short* woh = (short*)p; p += W_Q * 2;
  short* wol = (short*)p; p += W_Q * 2;
  short* wfh = (short*)p; p += W_FC * 2;
  short* wfl = (short*)p; p += W_FC * 2;
  short* wph = (short*)p; p += W_FC * 2;
  short* wpl = (short*)p; p += W_FC * 2;
  short* hwh = (short*)p; p += W_HD * 2;
  short* hwl = (short*)p; p += W_HD * 2;

  // ---- weight conversion (memory-bound) ----
  auto wc = [&](const float* s, short* h, short* l2, long n) {
    long n8 = n / 8;
    int blocks = (int)((n8 + 255) / 256);
    wcvt_kernel<<<blocks, 256, 0, stream>>>(s, h, l2, n8);
  };
  wc(Wq, wqh, wql, W_Q);
  wc(Wk, wkh, wkl, W_KV);
  wc(Wv, wvh, wvl, W_KV);
  wc(Wo, woh, wol, W_Q);
  wc(Wfc, wfh, wfl, W_FC);
  wc(Wp, wph, wpl, W_FC);
  wc(head_w, hwh, hwl, W_HD);

  embed_kernel<<<NTOK, 256, 0, stream>>>(ids, embed_w, big_w, big_proj,
                                         big_scale, ve_w, ve_proj, ve_scale,
                                         raw_x, vemb);
  smear_kernel<<<(int)(SZ_X / 256), 256, 0, stream>>>(raw_x, smear_gate, x, x0);

  for (int l = 0; l < Lc; ++l) {
    const float* mix = resid_mix + (size_t)l * 2 * Dc;
    prelayer_kernel<<<NTOK, 256, 0, stream>>>(x, x0, mix, x_in, xnh, xnl);
    // fused q,k,v projections
    qkv_db<<<dim3(NTOK / 64, 12), 256, 0, stream>>>(
        xnh, xnl, wqh + (size_t)l * Dc * Dc, wql + (size_t)l * Dc * Dc,
        wkh + (size_t)l * KVDc * Dc, wkl + (size_t)l * KVDc * Dc,
        wvh + (size_t)l * KVDc * Dc, wvl + (size_t)l * KVDc * Dc, qb, kb, vb,
        vemb, Dc);
    qkrope_kernel<<<NTOK, 256, 0, stream>>>(qb, kb, q_gain + (size_t)l * Hc);
    kvprep_kernel<<<dim3(Tc / 64, Bc * HKVc), 256, 0, stream>>>(
        kb, vb, khG, klG, vthG, vtlG);
    attn_mfma<<<dim3(Tc / 32, Bc * HKVc), 256, 0, stream>>>(
        qb, vb, khG, klG, vthG, vtlG, yh, yl);
    // out proj + residual: x = x_in + attn_scale * (y @ Wo.T)
    gemm_db64<<<dim3(NTOK / 64, Dc / 128), 256, 0, stream>>>(
        yh, yl, woh + (size_t)l * Dc * Dc, wol + (size_t)l * Dc * Dc, x, x_in,
        attn_scale + (size_t)l * Dc, Dc, Dc, 0);
    // MLP
    rms_split_kernel<<<NTOK, 256, 0, stream>>>(x, xnh, xnl);
    gemm_db128<<<dim3(NTOK / 128, MLPc / 128), 256, 0, stream>>>(
        xnh, xnl, wfh + (size_t)l * MLPc * Dc, wfl + (size_t)l * MLPc * Dc,
        nullptr, hh, hl, nullptr, nullptr, MLPc, Dc, 1);
    gemm_db64<<<dim3(NTOK / 64, Dc / 128), 256, 0, stream>>>(
        hh, hl, wph + (size_t)l * Dc * MLPc, wpl + (size_t)l * Dc * MLPc, x, x,
        mlp_scale + (size_t)l * Dc, Dc, MLPc, 0);
  }

  rms_split_kernel<<<NTOK, 256, 0, stream>>>(x, xnh, xnl);
  gemm_db128<<<dim3(NTOK / 128, (Vc + 127) / 128), 256, 0, stream>>>(
      xnh, xnl, hwh, hwl, out, nullptr, nullptr, nullptr, nullptr, Vc, Dc, 0);
}

// Round 5
// 5632.037 us; speedup vs baseline: 1.0283x; 1.0283x over previous
//
#include <hip/hip_runtime.h>
#include <hip/hip_bf16.h>

// Problem constants (match reference)
constexpr int Bc   = 2;
constexpr int Tc   = 1024;
constexpr int Vc   = 50257;
constexpr int Lc   = 8;
constexpr int Dc   = 1024;
constexpr int Hc   = 16;
constexpr int HKVc = 4;
constexpr int HDc  = 64;     // D/H
constexpr int KVDc = 256;    // HKV*HD
constexpr int MLPc = 4096;   // 4*D
constexpr int BVc  = 65536;
constexpr int BDc  = 256;
constexpr int VEDc = 128;

constexpr int NTOK = Bc * Tc;          // 2048
constexpr long SZ_X  = (long)NTOK * Dc;    // 2,097,152
constexpr long SZ_KV = (long)NTOK * KVDc;  // 524,288
constexpr long SZ_H  = (long)NTOK * MLPc;  // 8,388,608

constexpr long W_Q  = (long)Lc * Dc * Dc;     // 8,388,608
constexpr long W_KV = (long)Lc * KVDc * Dc;   // 2,097,152
constexpr long W_FC = (long)Lc * MLPc * Dc;   // 33,554,432
constexpr long W_HD = (long)Vc * Dc;          // 51,463,168
constexpr long SZ_KVP = (long)Bc * HKVc * (Tc / 64) * 4096;  // 524,288 shorts/plane

#define NEG_BIG (-3.0e38f)

typedef __attribute__((ext_vector_type(8))) short short8;    // 8 bf16 (4 VGPRs)
typedef __attribute__((ext_vector_type(4))) short short4v;   // 4 bf16 (8 B)
typedef __attribute__((ext_vector_type(4))) float floatx4;   // 16x16 MFMA acc
typedef __attribute__((ext_vector_type(16))) float floatx16; // 32x32 MFMA acc

__device__ __forceinline__ float wave_sum(float v) {
#pragma unroll
  for (int off = 32; off >= 1; off >>= 1) v += __shfl_xor(v, off);
  return v;
}

// Bijective XCD-aware swizzle (m204 formula).
__device__ __forceinline__ void xcd_swizzle(int& bx, int& by, int nbx, int nby) {
  int n = nbx * nby;
  int lin = by * nbx + bx;
  int q = n >> 3, rm = n & 7;
  int xcd = lin & 7, idx = lin >> 3;
  int v = (xcd < rm) ? (xcd * (q + 1) + idx)
                     : (rm * (q + 1) + (xcd - rm) * q + idx);
  bx = v % nbx;
  by = v / nbx;
}

// async global->LDS, 16B per lane. LDS dest = wave-uniform base + lane*16.
__device__ __forceinline__ void gll16(const void* g, void* l) {
  __builtin_amdgcn_global_load_lds(
      (const __attribute__((address_space(1))) unsigned int*)g,
      (__attribute__((address_space(3))) unsigned int*)l, 16, 0, 0);
}

// ---------------------------------------------------------------------------
// bf16 split helpers: f = bf2f(hi) + bf2f(lo) + O(2^-17 * f)
// ---------------------------------------------------------------------------
__device__ __forceinline__ short f2bf(float f) {
  unsigned u = __float_as_uint(f);
  return (short)((u + 0x7fffu + ((u >> 16) & 1u)) >> 16);
}
__device__ __forceinline__ float bf2f(short h) {
  return __uint_as_float(((unsigned)(unsigned short)h) << 16);
}

// ---------------------------------------------------------------------------
// Weight conversion: fp32 -> (hi, lo) bf16 planes. 8 elems/thread.
// ---------------------------------------------------------------------------
__global__ __launch_bounds__(256) void wcvt_kernel(
    const float* __restrict__ src, short* __restrict__ hi,
    short* __restrict__ lo, long n8) {
  long i = (long)blockIdx.x * 256 + threadIdx.x;
  if (i >= n8) return;
  const float* s = src + i * 8;
  float4 f0 = *(const float4*)s;
  float4 f1 = *(const float4*)(s + 4);
  float fv[8] = {f0.x, f0.y, f0.z, f0.w, f1.x, f1.y, f1.z, f1.w};
  short8 h8, l8;
#pragma unroll
  for (int e = 0; e < 8; ++e) {
    short hb = f2bf(fv[e]);
    h8[e] = hb;
    l8[e] = f2bf(fv[e] - bf2f(hb));
  }
  *(short8*)(hi + i * 8) = h8;
  *(short8*)(lo + i * 8) = l8;
}

// ---------------------------------------------------------------------------
// Embedding (unchanged)
// ---------------------------------------------------------------------------
__global__ __launch_bounds__(256) void embed_kernel(
    const int* __restrict__ ids, const float* __restrict__ embed_w,
    const float* __restrict__ big_w, const float* __restrict__ big_proj,
    const float* __restrict__ big_scale, const float* __restrict__ ve_w,
    const float* __restrict__ ve_proj, const float* __restrict__ ve_scale,
    float* __restrict__ raw_x, float* __restrict__ vemb) {
  int bt = blockIdx.x;
  int tid = threadIdx.x;
  int t = bt % Tc;
  int tok = ids[bt];

  const float* e = embed_w + (size_t)tok * Dc;
  float ev[4];
  float ss = 0.f;
#pragma unroll
  for (int i = 0; i < 4; ++i) {
    ev[i] = e[tid + i * 256];
    ss += ev[i] * ev[i];
  }
  __shared__ float red[4];
  __shared__ float brow[BDc];
  __shared__ float verow[VEDc];
  float wsum = wave_sum(ss);
  if ((tid & 63) == 0) red[tid >> 6] = wsum;

  int bg;
  if (t == 0) {
    bg = BVc - 1;
  } else {
    unsigned a = (unsigned)ids[bt];
    unsigned p = (unsigned)ids[bt - 1];
    bg = (int)(((36313u * a) ^ (27191u * p)) % 65535u);
  }
  brow[tid] = big_w[(size_t)bg * BDc + tid];
  if (tid < VEDc) verow[tid] = ve_w[(size_t)tok * VEDc + tid];
  __syncthreads();

  float tot = red[0] + red[1] + red[2] + red[3];
  float rn = rsqrtf(tot / (float)Dc + 1e-6f);
  float bs = big_scale[0];
#pragma unroll
  for (int i = 0; i < 4; ++i) {
    int d = tid + i * 256;
    const float* bp = big_proj + (size_t)d * BDc;
    float dot = 0.f;
    for (int c = 0; c < BDc; ++c) dot += brow[c] * bp[c];
    raw_x[(size_t)bt * Dc + d] = ev[i] * rn + dot * bs;
  }
  {
    float vs = ve_scale[0];
    int d = tid;
    const float* vp = ve_proj + (size_t)d * VEDc;
    float dot = 0.f;
    for (int c = 0; c < VEDc; ++c) dot += verow[c] * vp[c];
    vemb[(size_t)bt * KVDc + d] = dot * vs;
  }
}

// ---------------------------------------------------------------------------
// Smear (unchanged)
// ---------------------------------------------------------------------------
__global__ __launch_bounds__(256) void smear_kernel(
    const float* __restrict__ raw, const float* __restrict__ gate,
    float* __restrict__ x, float* __restrict__ x0) {
  long idx = (long)blockIdx.x * 256 + threadIdx.x;
  if (idx >= SZ_X) return;
  int d = (int)(idx & (Dc - 1));
  int t = (int)((idx / Dc) & (Tc - 1));
  float g = 1.f / (1.f + expf(-gate[d]));
  float cur = raw[idx];
  float prev = (t > 0) ? raw[idx - Dc] : 0.f;
  float val = (1.f - g) * cur + g * prev;
  x[idx] = val;
  x0[idx] = val;
}

// ---------------------------------------------------------------------------
// Pre-layer: x_in = mix0*x + mix1*x0 ; xn planes = split(rms(x_in)).
// ---------------------------------------------------------------------------
__global__ __launch_bounds__(256) void prelayer_kernel(
    const float* __restrict__ x, const float* __restrict__ x0,
    const float* __restrict__ mix, float* __restrict__ x_in,
    short* __restrict__ xnh, short* __restrict__ xnl) {
  int bt = blockIdx.x;
  int tid = threadIdx.x;
  const float* xr = x + (size_t)bt * Dc;
  const float* x0r = x0 + (size_t)bt * Dc;
  float vals[4];
  float ss = 0.f;
#pragma unroll
  for (int i = 0; i < 4; ++i) {
    int d = tid + i * 256;
    float v = mix[d] * xr[d] + mix[Dc + d] * x0r[d];
    vals[i] = v;
    ss += v * v;
  }
  __shared__ float red[4];
  float wsum = wave_sum(ss);
  if ((tid & 63) == 0) red[tid >> 6] = wsum;
  __syncthreads();
  float tot = red[0] + red[1] + red[2] + red[3];
  float rn = rsqrtf(tot / (float)Dc + 1e-6f);
#pragma unroll
  for (int i = 0; i < 4; ++i) {
    int d = tid + i * 256;
    size_t idx = (size_t)bt * Dc + d;
    x_in[idx] = vals[i];
    float vn = vals[i] * rn;
    short hb = f2bf(vn);
    xnh[idx] = hb;
    xnl[idx] = f2bf(vn - bf2f(hb));
  }
}

// ---------------------------------------------------------------------------
// RMS over D -> bf16 hi/lo planes. Block per token.
// ---------------------------------------------------------------------------
__global__ __launch_bounds__(256) void rms_split_kernel(
    const float* __restrict__ in, short* __restrict__ oh,
    short* __restrict__ ol) {
  int bt = blockIdx.x;
  int tid = threadIdx.x;
  const float* p = in + (size_t)bt * Dc;
  float v[4];
  float ss = 0.f;
#pragma unroll
  for (int i = 0; i < 4; ++i) {
    v[i] = p[tid + i * 256];
    ss += v[i] * v[i];
  }
  __shared__ float red[4];
  float wsum = wave_sum(ss);
  if ((tid & 63) == 0) red[tid >> 6] = wsum;
  __syncthreads();
  float tot = red[0] + red[1] + red[2] + red[3];
  float rn = rsqrtf(tot / (float)Dc + 1e-6f);
#pragma unroll
  for (int i = 0; i < 4; ++i) {
    size_t idx = (size_t)bt * Dc + tid + i * 256;
    float vn = v[i] * rn;
    short hb = f2bf(vn);
    oh[idx] = hb;
    ol[idx] = f2bf(vn - bf2f(hb));
  }
}

// ---------------------------------------------------------------------------
// Single-buffer plane GEMM body (bf16x2 split, 32x32x16 MFMA, m97 schedule):
//   C[M,N] = epi( A[M,K] @ W[N,K].T ),  A/W as bf16 hi/lo planes.
// Tile BM x BN, BK=32, 4 waves (2x2), wave tile (BM/2) x (BN/2).
// LDS frag order: subtile (rg,ks) = 32 rows x 16 k at (rg*2+ks)*1024B,
// lane l -> l*16B (row l&31, k-octet l>>5) => conflict-free b128, zero cvt.
// Schedule: issue global_load_lds -> barrier -> ds_read+MFMA -> barrier.
// Latency hidden by CU-level block interleave (small LDS => many blocks/CU).
// ---------------------------------------------------------------------------
template <int BM, int BN>
__device__ __forceinline__ void gemm_sb_body(
    const short* __restrict__ Ah, const short* __restrict__ Al,
    const short* __restrict__ Bh, const short* __restrict__ Bl,
    float* __restrict__ C, short* __restrict__ Ch, short* __restrict__ Cl,
    const float* __restrict__ base, const float* __restrict__ colscale,
    int m0, int n0, int N, int ldc, int K, int act, short* lds) {
  constexpr int RGA = BM / 32;
  constexpr int RGB = BN / 32;
  constexpr int SPW = RGA + RGB;        // wave-stages per K-step
  constexpr int PLA = RGA * 1024;       // shorts per A plane
  constexpr int PLB = RGB * 1024;
  constexpr int FI = BM / 64;
  constexpr int FJ = BN / 64;

  int tid = threadIdx.x, lane = tid & 63, wv = tid >> 6;

  const short* gsrc[SPW];
  int ldst[SPW];
#pragma unroll
  for (int t = 0; t < SPW; ++t) {
    int s = wv * SPW + t;
    const short* plane;
    int poff, rg, ks;
    if (s < RGA * 4) {
      int p = s / (RGA * 2);
      int rem = s % (RGA * 2);
      rg = rem >> 1; ks = rem & 1;
      plane = p ? Al : Ah;
      poff = p ? PLA : 0;
      int row = m0 + rg * 32 + (lane & 31);
      gsrc[t] = plane + (size_t)row * K + ks * 16 + (lane >> 5) * 8;
    } else {
      int s2 = s - RGA * 4;
      int p = s2 / (RGB * 2);
      int rem = s2 % (RGB * 2);
      rg = rem >> 1; ks = rem & 1;
      plane = p ? Bl : Bh;
      poff = 2 * PLA + (p ? PLB : 0);
      int row = n0 + rg * 32 + (lane & 31);
      if (row >= N) row = N - 1;  // tail clamp (head GEMM); col-guarded store
      gsrc[t] = plane + (size_t)row * K + ks * 16 + (lane >> 5) * 8;
    }
    ldst[t] = poff + (rg * 2 + ks) * 512;
  }

  int wm = (wv >> 1) * (BM / 2), wn = (wv & 1) * (BN / 2);
  floatx16 acc[FI][FJ] = {};

  const short* As_h = lds;
  const short* As_l = lds + PLA;
  const short* Bs_h = lds + 2 * PLA;
  const short* Bs_l = lds + 2 * PLA + PLB;

  for (int k0 = 0; k0 < K; k0 += 32) {
#pragma unroll
    for (int t = 0; t < SPW; ++t) gll16(gsrc[t], lds + ldst[t]);
#pragma unroll
    for (int t = 0; t < SPW; ++t) gsrc[t] += 32;
    __syncthreads();  // drains vmcnt: staged tile landed
#pragma unroll
    for (int ks = 0; ks < 2; ++ks) {
      short8 ah[FI], al2[FI], bh[FJ], bl2[FJ];
#pragma unroll
      for (int i = 0; i < FI; ++i) {
        int rg = (wm >> 5) + i;
        ah[i]  = *(const short8*)(As_h + (rg * 2 + ks) * 512 + lane * 8);
        al2[i] = *(const short8*)(As_l + (rg * 2 + ks) * 512 + lane * 8);
      }
#pragma unroll
      for (int j = 0; j < FJ; ++j) {
        int rg = (wn >> 5) + j;
        bh[j]  = *(const short8*)(Bs_h + (rg * 2 + ks) * 512 + lane * 8);
        bl2[j] = *(const short8*)(Bs_l + (rg * 2 + ks) * 512 + lane * 8);
      }
#pragma unroll
      for (int i = 0; i < FI; ++i)
#pragma unroll
        for (int j = 0; j < FJ; ++j) {
          acc[i][j] = __builtin_amdgcn_mfma_f32_32x32x16_bf16(ah[i], bh[j], acc[i][j], 0, 0, 0);
          acc[i][j] = __builtin_amdgcn_mfma_f32_32x32x16_bf16(ah[i], bl2[j], acc[i][j], 0, 0, 0);
          acc[i][j] = __builtin_amdgcn_mfma_f32_32x32x16_bf16(al2[i], bh[j], acc[i][j], 0, 0, 0);
        }
    }
    __syncthreads();  // protect LDS before next-tile overwrite
  }

  // epilogue: 32x32 C/D layout col=lane&31, row=(r&3)+8*(r>>2)+4*(lane>>5)
  int cl = lane & 31, g2 = lane >> 5;
#pragma unroll
  for (int i = 0; i < FI; ++i) {
#pragma unroll
    for (int j = 0; j < FJ; ++j) {
      int col = n0 + wn + 32 * j + cl;
      if (col >= N) continue;
      floatx16 f = acc[i][j];
#pragma unroll
      for (int r = 0; r < 16; ++r) {
        int row = m0 + wm + 32 * i + (r & 3) + 8 * (r >> 2) + 4 * g2;
        float v = f[r];
        if (act == 1) {
          float hx = (v >= 0.f) ? v : 0.5f * v;
          v = hx * hx;
        }
        if (colscale) v *= colscale[col];
        size_t idx = (size_t)row * ldc + col;
        if (base) v += base[idx];
        if (Ch) {
          short hb = f2bf(v);
          Ch[idx] = hb;
          Cl[idx] = f2bf(v - bf2f(hb));
        } else {
          C[idx] = v;
        }
      }
    }
  }
}

__global__ __launch_bounds__(256, 4) void gemm_sb128(
    const short* __restrict__ Ah, const short* __restrict__ Al,
    const short* __restrict__ Bh, const short* __restrict__ Bl,
    float* __restrict__ C, short* __restrict__ Ch, short* __restrict__ Cl,
    const float* __restrict__ base, const float* __restrict__ colscale, int N,
    int K, int act) {
  __shared__ short lds[16384];  // 32 KiB -> up to 5 blocks/CU
  int bx = blockIdx.x, by = blockIdx.y;
  xcd_swizzle(bx, by, gridDim.x, gridDim.y);
  gemm_sb_body<128, 128>(Ah, Al, Bh, Bl, C, Ch, Cl, base, colscale, bx * 128,
                         by * 128, N, N, K, act, lds);
}

__global__ __launch_bounds__(256, 4) void gemm_sb64(
    const short* __restrict__ Ah, const short* __restrict__ Al,
    const short* __restrict__ Bh, const short* __restrict__ Bl,
    float* __restrict__ C, const float* __restrict__ base,
    const float* __restrict__ colscale, int N, int K, int act) {
  __shared__ short lds[8192];  // 16 KiB -> up to 8 blocks/CU (VGPR-limited)
  int bx = blockIdx.x, by = blockIdx.y;
  xcd_swizzle(bx, by, gridDim.x, gridDim.y);
  gemm_sb_body<64, 64>(Ah, Al, Bh, Bl, C, nullptr, nullptr, base, colscale,
                       bx * 64, by * 64, N, N, K, act, lds);
}

// Fused q,k,v projection: grid (NTOK/64, 24). by<16 -> q, 16-19 -> k, 20-23 -> v.
__global__ __launch_bounds__(256, 4) void qkv_sb(
    const short* __restrict__ xnh, const short* __restrict__ xnl,
    const short* __restrict__ wqh, const short* __restrict__ wql,
    const short* __restrict__ wkh, const short* __restrict__ wkl,
    const short* __restrict__ wvh, const short* __restrict__ wvl,
    float* __restrict__ qb, float* __restrict__ kb, float* __restrict__ vb,
    const float* __restrict__ vemb, int K) {
  __shared__ short lds[8192];
  int bx = blockIdx.x, by = blockIdx.y;
  xcd_swizzle(bx, by, gridDim.x, gridDim.y);
  const short *Bh, *Bl;
  float* C;
  const float* base = nullptr;
  int n0, ldn;
  if (by < 16) {
    Bh = wqh; Bl = wql; C = qb; n0 = by * 64; ldn = Dc;
  } else if (by < 20) {
    Bh = wkh; Bl = wkl; C = kb; n0 = (by - 16) * 64; ldn = KVDc;
  } else {
    Bh = wvh; Bl = wvl; C = vb; base = vemb; n0 = (by - 20) * 64; ldn = KVDc;
  }
  gemm_sb_body<64, 64>(xnh, xnl, Bh, Bl, C, nullptr, nullptr, base, nullptr,
                       bx * 64, n0, ldn, ldn, K, 0, lds);
}

// ---------------------------------------------------------------------------
// QK head-RMS + RoPE (+q_gain). Block per token. (unchanged)
// ---------------------------------------------------------------------------
__global__ __launch_bounds__(256) void qkrope_kernel(
    float* __restrict__ q, float* __restrict__ k,
    const float* __restrict__ q_gain) {
  int bt = blockIdx.x;
  int t = bt % Tc;
  int tid = threadIdx.x;
  int lane = tid & 63, wv = tid >> 6;
  int fi = lane & 31;
  float inv = expf(-(float)(2 * fi) * (9.210340372f / 64.f));
  float ang = (float)t * inv;
  float cv = cosf(ang);
  float sv = sinf(ang);

#pragma unroll
  for (int hh = 0; hh < 4; ++hh) {
    int h = wv + hh * 4;
    float* qp = q + (size_t)bt * Dc + h * 64;
    float val = qp[lane];
    float ss = wave_sum(val * val);
    float rn = rsqrtf(ss / 64.f + 1e-6f);
    val *= rn;
    float partner = __shfl(val, lane ^ 32);
    float out = (lane < 32) ? (val * cv + partner * sv) : (val * cv - partner * sv);
    out *= q_gain[h];
    qp[lane] = out;
  }
  {
    int h = wv;
    float* kp = k + (size_t)bt * KVDc + h * 64;
    float val = kp[lane];
    float ss = wave_sum(val * val);
    float rn = rsqrtf(ss / 64.f + 1e-6f);
    val *= rn;
    float partner = __shfl(val, lane ^ 32);
    float out = (lane < 32) ? (val * cv + partner * sv) : (val * cv - partner * sv);
    kp[lane] = out;
  }
}

// ---------------------------------------------------------------------------
// K/V^T frag-order plane prep (unchanged).
// ---------------------------------------------------------------------------
__global__ __launch_bounds__(256) void kvprep_kernel(
    const float* __restrict__ kb, const float* __restrict__ vb,
    short* __restrict__ khG, short* __restrict__ klG,
    short* __restrict__ vthG, short* __restrict__ vtlG) {
  __shared__ float kf[64][65];
  __shared__ float vf[64][65];
  int kt = blockIdx.x, bh = blockIdx.y;
  int b = bh >> 2, hkv = bh & 3;
  int tid = threadIdx.x;
#pragma unroll
  for (int u = 0; u < 4; ++u) {
    int idx = tid + u * 256;  // 0..1023 float4 units
    int row = idx >> 4, c4 = idx & 15;
    size_t off = ((size_t)(b * Tc + kt * 64 + row)) * KVDc + hkv * 64 + c4 * 4;
    float4 k4 = *(const float4*)(kb + off);
    float4 v4 = *(const float4*)(vb + off);
    kf[row][c4 * 4 + 0] = k4.x; kf[row][c4 * 4 + 1] = k4.y;
    kf[row][c4 * 4 + 2] = k4.z; kf[row][c4 * 4 + 3] = k4.w;
    vf[row][c4 * 4 + 0] = v4.x; vf[row][c4 * 4 + 1] = v4.y;
    vf[row][c4 * 4 + 2] = v4.z; vf[row][c4 * 4 + 3] = v4.w;
  }
  __syncthreads();
  size_t gb = ((size_t)(bh * (Tc / 64) + kt)) * 4096;
#pragma unroll
  for (int u = 0; u < 2; ++u) {
    int unit = tid + u * 256;  // 0..511
    int s = unit >> 6, p = unit & 63;
    {  // K plane
      int half = s >> 2, rg = s & 3;
      int row = rg * 16 + (p & 15);
      int d0 = half * 32 + (p >> 4) * 8;
      short8 h8, l8;
#pragma unroll
      for (int e = 0; e < 8; ++e) {
        float v = kf[row][d0 + e];
        short hb = f2bf(v);
        h8[e] = hb;
        l8[e] = f2bf(v - bf2f(hb));
      }
      *(short8*)(khG + gb + s * 512 + p * 8) = h8;
      *(short8*)(klG + gb + s * 512 + p * 8) = l8;
    }
    {  // V^T plane
      int ks = s >> 2, jd = s & 3;
      int d = jd * 16 + (p & 15);
      int k0 = ks * 32 + (p >> 4) * 8;
      short8 h8, l8;
#pragma unroll
      for (int e = 0; e < 8; ++e) {
        float v = vf[k0 + e][d];
        short hb = f2bf(v);
        h8[e] = hb;
        l8[e] = f2bf(v - bf2f(hb));
      }
      *(short8*)(vthG + gb + s * 512 + p * 8) = h8;
      *(short8*)(vtlG + gb + s * 512 + p * 8) = l8;
    }
  }
}

// ---------------------------------------------------------------------------
// MFMA causal GQA flash attention + v-direction-removal epilogue (unchanged).
// ---------------------------------------------------------------------------
__global__ __launch_bounds__(256) void attn_mfma(
    const float* __restrict__ qg_, const float* __restrict__ vg_,
    const short* __restrict__ khG, const short* __restrict__ klG,
    const short* __restrict__ vthG, const short* __restrict__ vtlG,
    short* __restrict__ yh_, short* __restrict__ yl_) {
  __shared__ short smem[32768];  // 64 KiB
  short* Khi  = smem;
  short* Klo  = smem + 4096;
  short* Vthi = smem + 8192;
  short* Vtlo = smem + 12288;

  int qt = blockIdx.x;
  int bh = blockIdx.y;
  int b = bh >> 2, hkv = bh & 3;
  int tid = threadIdx.x;
  int lane = tid & 63, wv = tid >> 6;
  int x = lane & 15, g = lane >> 4;
  int h = hkv * 4 + wv;
  int qbase = qt * 32;

  short* PAhi = smem + 16384 + wv * 2048;
  short* PAlo = smem + 24576 + wv * 2048;

  short8 qh[2][2], qlo[2][2];
#pragma unroll
  for (int j = 0; j < 2; ++j)
#pragma unroll
    for (int ks = 0; ks < 2; ++ks) {
      int qrow = qbase + 16 * j + x;
      const float* qp =
          qg_ + ((size_t)(b * Tc + qrow)) * Dc + h * 64 + ks * 32 + g * 8;
      float4 f0 = *(const float4*)qp;
      float4 f1 = *(const float4*)(qp + 4);
      float fv[8] = {f0.x, f0.y, f0.z, f0.w, f1.x, f1.y, f1.z, f1.w};
#pragma unroll
      for (int e = 0; e < 8; ++e) {
        short hb = f2bf(fv[e]);
        qh[j][ks][e] = hb;
        qlo[j][ks][e] = f2bf(fv[e] - bf2f(hb));
      }
    }

  // per-wave staging source (wave wv stages plane wv: Khi/Klo/Vthi/Vtlo)
  const short* planes[4] = {khG, klG, vthG, vtlG};
  const short* gplane = planes[wv] + ((size_t)bh * (Tc / 64)) * 4096 + lane * 8;
  short* lplane = smem + wv * 4096;

  floatx4 o[2][4] = {};
  float m_run[2] = {NEG_BIG, NEG_BIG};
  float l_run[2] = {0.f, 0.f};

  int nkt = (qbase >> 6) + 1;
  for (int kt = 0; kt < nkt; ++kt) {
    const short* gs = gplane + (size_t)kt * 4096;
#pragma unroll
    for (int t = 0; t < 8; ++t) gll16(gs + t * 512, lplane + t * 512);
    __syncthreads();

    floatx4 st[4][2] = {};
#pragma unroll
    for (int ks = 0; ks < 2; ++ks) {
#pragma unroll
      for (int i = 0; i < 4; ++i) {
        short8 ka_h = *(const short8*)(Khi + ks * 2048 + i * 512 + lane * 8);
        short8 ka_l = *(const short8*)(Klo + ks * 2048 + i * 512 + lane * 8);
#pragma unroll
        for (int j = 0; j < 2; ++j) {
          st[i][j] = __builtin_amdgcn_mfma_f32_16x16x32_bf16(ka_h, qh[j][ks], st[i][j], 0, 0, 0);
          st[i][j] = __builtin_amdgcn_mfma_f32_16x16x32_bf16(ka_h, qlo[j][ks], st[i][j], 0, 0, 0);
          st[i][j] = __builtin_amdgcn_mfma_f32_16x16x32_bf16(ka_l, qh[j][ks], st[i][j], 0, 0, 0);
        }
      }
    }

    float al[2];
#pragma unroll
    for (int j = 0; j < 2; ++j) {
      int qrow = qbase + 16 * j + x;
      float mx = NEG_BIG;
#pragma unroll
      for (int i = 0; i < 4; ++i) {
#pragma unroll
        for (int r = 0; r < 4; ++r) {
          int krow = kt * 64 + 16 * i + 4 * g + r;
          float s = st[i][j][r] * 0.125f;
          if (krow > qrow) s = NEG_BIG;
          st[i][j][r] = s;
          mx = fmaxf(mx, s);
        }
      }
      mx = fmaxf(mx, __shfl_xor(mx, 16));
      mx = fmaxf(mx, __shfl_xor(mx, 32));
      float m_new = fmaxf(m_run[j], mx);
      al[j] = __expf(m_run[j] - m_new);
      float ts = 0.f;
#pragma unroll
      for (int i = 0; i < 4; ++i) {
#pragma unroll
        for (int r = 0; r < 4; ++r) {
          float p = __expf(st[i][j][r] - m_new);
          st[i][j][r] = p;
          ts += p;
        }
      }
      ts += __shfl_xor(ts, 16);
      ts += __shfl_xor(ts, 32);
      l_run[j] = l_run[j] * al[j] + ts;
      m_run[j] = m_new;
    }

#pragma unroll
    for (int j = 0; j < 2; ++j) {
#pragma unroll
      for (int i = 0; i < 4; ++i) {
        short4v h4, l4;
#pragma unroll
        for (int r = 0; r < 4; ++r) {
          float p = st[i][j][r];
          short hb = f2bf(p);
          h4[r] = hb;
          l4[r] = f2bf(p - bf2f(hb));
        }
        int offp = (i >> 1) * 1024 + j * 512 +
                   (x + (2 * (i & 1) + (g >> 1)) * 16) * 8 + 4 * (g & 1);
        *(short4v*)(PAhi + offp) = h4;
        *(short4v*)(PAlo + offp) = l4;
      }
    }

#pragma unroll
    for (int iO = 0; iO < 2; ++iO) {
#pragma unroll
      for (int r = 0; r < 4; ++r) {
        float a = __shfl(al[iO], 4 * g + r);
#pragma unroll
        for (int jd = 0; jd < 4; ++jd) o[iO][jd][r] *= a;
      }
    }
    __syncthreads();

#pragma unroll
    for (int ks = 0; ks < 2; ++ks) {
      short8 pa_h[2], pa_l[2];
#pragma unroll
      for (int iO = 0; iO < 2; ++iO) {
        pa_h[iO] = *(const short8*)(PAhi + ks * 1024 + iO * 512 + lane * 8);
        pa_l[iO] = *(const short8*)(PAlo + ks * 1024 + iO * 512 + lane * 8);
      }
#pragma unroll
      for (int jd = 0; jd < 4; ++jd) {
        short8 vb_h = *(const short8*)(Vthi + ks * 2048 + jd * 512 + lane * 8);
        short8 vb_l = *(const short8*)(Vtlo + ks * 2048 + jd * 512 + lane * 8);
#pragma unroll
        for (int iO = 0; iO < 2; ++iO) {
          o[iO][jd] = __builtin_amdgcn_mfma_f32_16x16x32_bf16(pa_h[iO], vb_h, o[iO][jd], 0, 0, 0);
          o[iO][jd] = __builtin_amdgcn_mfma_f32_16x16x32_bf16(pa_h[iO], vb_l, o[iO][jd], 0, 0, 0);
          o[iO][jd] = __builtin_amdgcn_mfma_f32_16x16x32_bf16(pa_l[iO], vb_h, o[iO][jd], 0, 0, 0);
        }
      }
    }
    __syncthreads();
  }

#pragma unroll
  for (int iO = 0; iO < 2; ++iO) {
#pragma unroll
    for (int r = 0; r < 4; ++r) {
      float lr = __shfl(l_run[iO], 4 * g + r);
      float rcp = 1.f / lr;
      int qrow = qbase + 16 * iO + 4 * g + r;
      const float* vr = vg_ + ((size_t)(b * Tc + qrow)) * KVDc + hkv * 64;
      float vv[4], oo[4];
      float pn = 0.f, pd = 0.f;
#pragma unroll
      for (int jd = 0; jd < 4; ++jd) {
        vv[jd] = vr[16 * jd + x];
        oo[jd] = o[iO][jd][r] * rcp;
        pn += vv[jd] * vv[jd];
        pd += oo[jd] * vv[jd];
      }
#pragma unroll
      for (int off = 1; off <= 8; off <<= 1) {
        pn += __shfl_xor(pn, off);
        pd += __shfl_xor(pd, off);
      }
      float nrm = sqrtf(pn);
      float mxv = fmaxf(nrm, 1e-12f);
      float si = 1.f / mxv;
      float co = pd * si * si;
      size_t ybase = ((size_t)(b * Tc + qrow)) * Dc + h * 64;
#pragma unroll
      for (int jd = 0; jd < 4; ++jd) {
        float val = oo[jd] - co * vv[jd];
        short hb = f2bf(val);
        yh_[ybase + 16 * jd + x] = hb;
        yl_[ybase + 16 * jd + x] = f2bf(val - bf2f(hb));
      }
    }
  }
}

// ---------------------------------------------------------------------------
extern "C" void kernel_launch(void* const* d_in, const int* in_sizes, int n_in,
                              void* d_out, int out_size, void* d_ws,
                              size_t ws_size, hipStream_t stream) {
  const int* ids          = (const int*)d_in[0];
  const float* embed_w    = (const float*)d_in[1];
  const float* big_w      = (const float*)d_in[2];
  const float* big_proj   = (const float*)d_in[3];
  const float* big_scale  = (const float*)d_in[4];
  const float* smear_gate = (const float*)d_in[5];
  const float* ve_w       = (const float*)d_in[6];
  const float* ve_proj    = (const float*)d_in[7];
  const float* ve_scale   = (const float*)d_in[8];
  const float* Wq         = (const float*)d_in[9];
  const float* Wk         = (const float*)d_in[10];
  const float* Wv         = (const float*)d_in[11];
  const float* Wo         = (const float*)d_in[12];
  const float* q_gain     = (const float*)d_in[13];
  const float* attn_scale = (const float*)d_in[14];
  const float* mlp_scale  = (const float*)d_in[15];
  const float* resid_mix  = (const float*)d_in[16];
  const float* Wfc        = (const float*)d_in[17];
  const float* Wp         = (const float*)d_in[18];
  const float* head_w     = (const float*)d_in[19];
  float* out = (float*)d_out;

  // ---- workspace layout ----
  char* p = (char*)d_ws;
  float* x     = (float*)p; p += SZ_X * 4;
  float* x0    = (float*)p; p += SZ_X * 4;
  float* x_in  = (float*)p; p += SZ_X * 4;
  float* qb    = (float*)p; p += SZ_X * 4;
  float* kb    = (float*)p; p += SZ_KV * 4;
  float* vb    = (float*)p; p += SZ_KV * 4;
  float* vemb  = (float*)p; p += SZ_KV * 4;
  float* raw_x = (float*)p; p += SZ_X * 4;
  short* xnh = (short*)p; p += SZ_X * 2;
  short* xnl = (short*)p; p += SZ_X * 2;
  short* yh  = (short*)p; p += SZ_X * 2;
  short* yl  = (short*)p; p += SZ_X * 2;
  short* hh  = (short*)p; p += SZ_H * 2;
  short* hl  = (short*)p; p += SZ_H * 2;
  short* khG  = (short*)p; p += SZ_KVP * 2;
  short* klG  = (short*)p; p += SZ_KVP * 2;
  short* vthG = (short*)p; p += SZ_KVP * 2;
  short* vtlG = (short*)p; p += SZ_KVP * 2;
  short* wqh = (short*)p; p += W_Q * 2;
  short* wql = (short*)p; p += W_Q * 2;
  short* wkh = (short*)p; p += W_KV * 2;
  short* wkl = (short*)p; p += W_KV * 2;
  short* wvh = (short*)p; p += W_KV * 2;
  short* wvl = (short*)p; p += W_KV * 2;
  short* woh = (short*)p; p += W_Q * 2;
  short* wol = (short*)p; p += W_Q * 2;
  short* wfh = (short*)p; p += W_FC * 2;
  short* wfl = (short*)p; p += W_FC * 2;
  short* wph = (short*)p; p += W_FC * 2;
  short* wpl = (short*)p; p += W_FC * 2;
  short* hwh = (short*)p; p += W_HD * 2;
  short* hwl = (short*)p; p += W_HD * 2;

  // ---- weight conversion (memory-bound) ----
  auto wc = [&](const float* s, short* h, short* l2, long n) {
    long n8 = n / 8;
    int blocks = (int)((n8 + 255) / 256);
    wcvt_kernel<<<blocks, 256, 0, stream>>>(s, h, l2, n8);
  };
  wc(Wq, wqh, wql, W_Q);
  wc(Wk, wkh, wkl, W_KV);
  wc(Wv, wvh, wvl, W_KV);
  wc(Wo, woh, wol, W_Q);
  wc(Wfc, wfh, wfl, W_FC);
  wc(Wp, wph, wpl, W_FC);
  wc(head_w, hwh, hwl, W_HD);

  embed_kernel<<<NTOK, 256, 0, stream>>>(ids, embed_w, big_w, big_proj,
                                         big_scale, ve_w, ve_proj, ve_scale,
                                         raw_x, vemb);
  smear_kernel<<<(int)(SZ_X / 256), 256, 0, stream>>>(raw_x, smear_gate, x, x0);

  for (int l = 0; l < Lc; ++l) {
    const float* mix = resid_mix + (size_t)l * 2 * Dc;
    prelayer_kernel<<<NTOK, 256, 0, stream>>>(x, x0, mix, x_in, xnh, xnl);
    // fused q,k,v projections (768 blocks)
    qkv_sb<<<dim3(NTOK / 64, 24), 256, 0, stream>>>(
        xnh, xnl, wqh + (size_t)l * Dc * Dc, wql + (size_t)l * Dc * Dc,
        wkh + (size_t)l * KVDc * Dc, wkl + (size_t)l * KVDc * Dc,
        wvh + (size_t)l * KVDc * Dc, wvl + (size_t)l * KVDc * Dc, qb, kb, vb,
        vemb, Dc);
    qkrope_kernel<<<NTOK, 256, 0, stream>>>(qb, kb, q_gain + (size_t)l * Hc);
    kvprep_kernel<<<dim3(Tc / 64, Bc * HKVc), 256, 0, stream>>>(
        kb, vb, khG, klG, vthG, vtlG);
    attn_mfma<<<dim3(Tc / 32, Bc * HKVc), 256, 0, stream>>>(
        qb, vb, khG, klG, vthG, vtlG, yh, yl);
    // out proj + residual: x = x_in + attn_scale * (y @ Wo.T)  (512 blocks)
    gemm_sb64<<<dim3(NTOK / 64, Dc / 64), 256, 0, stream>>>(
        yh, yl, woh + (size_t)l * Dc * Dc, wol + (size_t)l * Dc * Dc, x, x_in,
        attn_scale + (size_t)l * Dc, Dc, Dc, 0);
    // MLP
    rms_split_kernel<<<NTOK, 256, 0, stream>>>(x, xnh, xnl);
    gemm_sb128<<<dim3(NTOK / 128, MLPc / 128), 256, 0, stream>>>(
        xnh, xnl, wfh + (size_t)l * MLPc * Dc, wfl + (size_t)l * MLPc * Dc,
        nullptr, hh, hl, nullptr, nullptr, MLPc, Dc, 1);
    gemm_sb64<<<dim3(NTOK / 64, Dc / 64), 256, 0, stream>>>(
        hh, hl, wph + (size_t)l * Dc * MLPc, wpl + (size_t)l * Dc * MLPc, x, x,
        mlp_scale + (size_t)l * Dc, Dc, MLPc, 0);
  }

  rms_split_kernel<<<NTOK, 256, 0, stream>>>(x, xnh, xnl);
  gemm_sb128<<<dim3(NTOK / 128, (Vc + 127) / 128), 256, 0, stream>>>(
      xnh, xnl, hwh, hwl, out, nullptr, nullptr, nullptr, nullptr, Vc, Dc, 0);
}

// Round 6
// 5397.829 us; speedup vs baseline: 1.0729x; 1.0434x over previous
//
#include <hip/hip_runtime.h>
#include <hip/hip_bf16.h>

// Problem constants (match reference)
constexpr int Bc   = 2;
constexpr int Tc   = 1024;
constexpr int Vc   = 50257;
constexpr int Lc   = 8;
constexpr int Dc   = 1024;
constexpr int Hc   = 16;
constexpr int HKVc = 4;
constexpr int HDc  = 64;     // D/H
constexpr int KVDc = 256;    // HKV*HD
constexpr int MLPc = 4096;   // 4*D
constexpr int BVc  = 65536;
constexpr int BDc  = 256;
constexpr int VEDc = 128;

constexpr int NTOK = Bc * Tc;          // 2048
constexpr long SZ_X  = (long)NTOK * Dc;    // 2,097,152
constexpr long SZ_KV = (long)NTOK * KVDc;  // 524,288
constexpr long SZ_H  = (long)NTOK * MLPc;  // 8,388,608

constexpr long W_Q  = (long)Lc * Dc * Dc;     // 8,388,608
constexpr long W_KV = (long)Lc * KVDc * Dc;   // 2,097,152
constexpr long W_FC = (long)Lc * MLPc * Dc;   // 33,554,432
constexpr long W_HD = (long)Vc * Dc;          // 51,463,168
constexpr long SZ_KVP = (long)Bc * HKVc * (Tc / 64) * 4096;  // 524,288 shorts/plane

#define NEG_BIG (-3.0e38f)

typedef __attribute__((ext_vector_type(8))) short short8;    // 8 bf16 (4 VGPRs)
typedef __attribute__((ext_vector_type(4))) short short4v;   // 4 bf16 (8 B)
typedef __attribute__((ext_vector_type(4))) float floatx4;   // 16x16 MFMA acc
typedef __attribute__((ext_vector_type(16))) float floatx16; // 32x32 MFMA acc

__device__ __forceinline__ float wave_sum(float v) {
#pragma unroll
  for (int off = 32; off >= 1; off >>= 1) v += __shfl_xor(v, off);
  return v;
}

// Bijective XCD-aware swizzle (m204 formula).
__device__ __forceinline__ void xcd_swizzle(int& bx, int& by, int nbx, int nby) {
  int n = nbx * nby;
  int lin = by * nbx + bx;
  int q = n >> 3, rm = n & 7;
  int xcd = lin & 7, idx = lin >> 3;
  int v = (xcd < rm) ? (xcd * (q + 1) + idx)
                     : (rm * (q + 1) + (xcd - rm) * q + idx);
  bx = v % nbx;
  by = v / nbx;
}

// async global->LDS, 16B per lane. LDS dest = wave-uniform base + lane*16.
__device__ __forceinline__ void gll16(const void* g, void* l) {
  __builtin_amdgcn_global_load_lds(
      (const __attribute__((address_space(1))) unsigned int*)g,
      (__attribute__((address_space(3))) unsigned int*)l, 16, 0, 0);
}

// ---------------------------------------------------------------------------
// bf16 split helpers: f = bf2f(hi) + bf2f(lo) + O(2^-17 * f)
// ---------------------------------------------------------------------------
__device__ __forceinline__ short f2bf(float f) {
  unsigned u = __float_as_uint(f);
  return (short)((u + 0x7fffu + ((u >> 16) & 1u)) >> 16);
}
__device__ __forceinline__ float bf2f(short h) {
  return __uint_as_float(((unsigned)(unsigned short)h) << 16);
}

// ---------------------------------------------------------------------------
// Weight conversion: fp32 -> (hi, lo) bf16 planes. 8 elems/thread.
// ---------------------------------------------------------------------------
__global__ __launch_bounds__(256) void wcvt_kernel(
    const float* __restrict__ src, short* __restrict__ hi,
    short* __restrict__ lo, long n8) {
  long i = (long)blockIdx.x * 256 + threadIdx.x;
  if (i >= n8) return;
  const float* s = src + i * 8;
  float4 f0 = *(const float4*)s;
  float4 f1 = *(const float4*)(s + 4);
  float fv[8] = {f0.x, f0.y, f0.z, f0.w, f1.x, f1.y, f1.z, f1.w};
  short8 h8, l8;
#pragma unroll
  for (int e = 0; e < 8; ++e) {
    short hb = f2bf(fv[e]);
    h8[e] = hb;
    l8[e] = f2bf(fv[e] - bf2f(hb));
  }
  *(short8*)(hi + i * 8) = h8;
  *(short8*)(lo + i * 8) = l8;
}

// ---------------------------------------------------------------------------
// Embedding (unchanged)
// ---------------------------------------------------------------------------
__global__ __launch_bounds__(256) void embed_kernel(
    const int* __restrict__ ids, const float* __restrict__ embed_w,
    const float* __restrict__ big_w, const float* __restrict__ big_proj,
    const float* __restrict__ big_scale, const float* __restrict__ ve_w,
    const float* __restrict__ ve_proj, const float* __restrict__ ve_scale,
    float* __restrict__ raw_x, float* __restrict__ vemb) {
  int bt = blockIdx.x;
  int tid = threadIdx.x;
  int t = bt % Tc;
  int tok = ids[bt];

  const float* e = embed_w + (size_t)tok * Dc;
  float ev[4];
  float ss = 0.f;
#pragma unroll
  for (int i = 0; i < 4; ++i) {
    ev[i] = e[tid + i * 256];
    ss += ev[i] * ev[i];
  }
  __shared__ float red[4];
  __shared__ float brow[BDc];
  __shared__ float verow[VEDc];
  float wsum = wave_sum(ss);
  if ((tid & 63) == 0) red[tid >> 6] = wsum;

  int bg;
  if (t == 0) {
    bg = BVc - 1;
  } else {
    unsigned a = (unsigned)ids[bt];
    unsigned p = (unsigned)ids[bt - 1];
    bg = (int)(((36313u * a) ^ (27191u * p)) % 65535u);
  }
  brow[tid] = big_w[(size_t)bg * BDc + tid];
  if (tid < VEDc) verow[tid] = ve_w[(size_t)tok * VEDc + tid];
  __syncthreads();

  float tot = red[0] + red[1] + red[2] + red[3];
  float rn = rsqrtf(tot / (float)Dc + 1e-6f);
  float bs = big_scale[0];
#pragma unroll
  for (int i = 0; i < 4; ++i) {
    int d = tid + i * 256;
    const float* bp = big_proj + (size_t)d * BDc;
    float dot = 0.f;
    for (int c = 0; c < BDc; ++c) dot += brow[c] * bp[c];
    raw_x[(size_t)bt * Dc + d] = ev[i] * rn + dot * bs;
  }
  {
    float vs = ve_scale[0];
    int d = tid;
    const float* vp = ve_proj + (size_t)d * VEDc;
    float dot = 0.f;
    for (int c = 0; c < VEDc; ++c) dot += verow[c] * vp[c];
    vemb[(size_t)bt * KVDc + d] = dot * vs;
  }
}

// ---------------------------------------------------------------------------
// Smear (unchanged)
// ---------------------------------------------------------------------------
__global__ __launch_bounds__(256) void smear_kernel(
    const float* __restrict__ raw, const float* __restrict__ gate,
    float* __restrict__ x, float* __restrict__ x0) {
  long idx = (long)blockIdx.x * 256 + threadIdx.x;
  if (idx >= SZ_X) return;
  int d = (int)(idx & (Dc - 1));
  int t = (int)((idx / Dc) & (Tc - 1));
  float g = 1.f / (1.f + expf(-gate[d]));
  float cur = raw[idx];
  float prev = (t > 0) ? raw[idx - Dc] : 0.f;
  float val = (1.f - g) * cur + g * prev;
  x[idx] = val;
  x0[idx] = val;
}

// ---------------------------------------------------------------------------
// Pre-layer: x_in = mix0*x + mix1*x0 ; xn planes = split(rms(x_in)).
// ---------------------------------------------------------------------------
__global__ __launch_bounds__(256) void prelayer_kernel(
    const float* __restrict__ x, const float* __restrict__ x0,
    const float* __restrict__ mix, float* __restrict__ x_in,
    short* __restrict__ xnh, short* __restrict__ xnl) {
  int bt = blockIdx.x;
  int tid = threadIdx.x;
  const float* xr = x + (size_t)bt * Dc;
  const float* x0r = x0 + (size_t)bt * Dc;
  float vals[4];
  float ss = 0.f;
#pragma unroll
  for (int i = 0; i < 4; ++i) {
    int d = tid + i * 256;
    float v = mix[d] * xr[d] + mix[Dc + d] * x0r[d];
    vals[i] = v;
    ss += v * v;
  }
  __shared__ float red[4];
  float wsum = wave_sum(ss);
  if ((tid & 63) == 0) red[tid >> 6] = wsum;
  __syncthreads();
  float tot = red[0] + red[1] + red[2] + red[3];
  float rn = rsqrtf(tot / (float)Dc + 1e-6f);
#pragma unroll
  for (int i = 0; i < 4; ++i) {
    int d = tid + i * 256;
    size_t idx = (size_t)bt * Dc + d;
    x_in[idx] = vals[i];
    float vn = vals[i] * rn;
    short hb = f2bf(vn);
    xnh[idx] = hb;
    xnl[idx] = f2bf(vn - bf2f(hb));
  }
}

// ---------------------------------------------------------------------------
// RMS over D -> bf16 hi/lo planes. Block per token.
// ---------------------------------------------------------------------------
__global__ __launch_bounds__(256) void rms_split_kernel(
    const float* __restrict__ in, short* __restrict__ oh,
    short* __restrict__ ol) {
  int bt = blockIdx.x;
  int tid = threadIdx.x;
  const float* p = in + (size_t)bt * Dc;
  float v[4];
  float ss = 0.f;
#pragma unroll
  for (int i = 0; i < 4; ++i) {
    v[i] = p[tid + i * 256];
    ss += v[i] * v[i];
  }
  __shared__ float red[4];
  float wsum = wave_sum(ss);
  if ((tid & 63) == 0) red[tid >> 6] = wsum;
  __syncthreads();
  float tot = red[0] + red[1] + red[2] + red[3];
  float rn = rsqrtf(tot / (float)Dc + 1e-6f);
#pragma unroll
  for (int i = 0; i < 4; ++i) {
    size_t idx = (size_t)bt * Dc + tid + i * 256;
    float vn = v[i] * rn;
    short hb = f2bf(vn);
    oh[idx] = hb;
    ol[idx] = f2bf(vn - bf2f(hb));
  }
}

// ---------------------------------------------------------------------------
// Single-buffer plane GEMM body (bf16x2 split, 32x32x16 MFMA), 2-phase overlap:
//   barrier(tile landed) -> ds_read ALL frags to regs -> barrier(LDS free)
//   -> issue next tile's global_load_lds -> MFMA cluster (overlaps loads).
// Tile BM x BN, BK=32, 4 waves (2x2), wave tile (BM/2) x (BN/2).
// LDS frag order: subtile (rg,ks) = 32 rows x 16 k at (rg*2+ks)*1024B,
// lane l -> l*16B (row l&31, k-octet l>>5) => conflict-free b128, zero cvt.
// ---------------------------------------------------------------------------
template <int BM, int BN>
__device__ __forceinline__ void gemm_sb_body(
    const short* __restrict__ Ah, const short* __restrict__ Al,
    const short* __restrict__ Bh, const short* __restrict__ Bl,
    float* __restrict__ C, short* __restrict__ Ch, short* __restrict__ Cl,
    const float* __restrict__ base, const float* __restrict__ colscale,
    int m0, int n0, int N, int ldc, int K, int act, short* lds) {
  constexpr int RGA = BM / 32;
  constexpr int RGB = BN / 32;
  constexpr int SPW = RGA + RGB;        // wave-stages per K-step
  constexpr int PLA = RGA * 1024;       // shorts per A plane
  constexpr int PLB = RGB * 1024;
  constexpr int FI = BM / 64;
  constexpr int FJ = BN / 64;

  int tid = threadIdx.x, lane = tid & 63, wv = tid >> 6;

  const short* gsrc[SPW];
  int ldst[SPW];
#pragma unroll
  for (int t = 0; t < SPW; ++t) {
    int s = wv * SPW + t;
    const short* plane;
    int poff, rg, ks;
    if (s < RGA * 4) {
      int p = s / (RGA * 2);
      int rem = s % (RGA * 2);
      rg = rem >> 1; ks = rem & 1;
      plane = p ? Al : Ah;
      poff = p ? PLA : 0;
      int row = m0 + rg * 32 + (lane & 31);
      gsrc[t] = plane + (size_t)row * K + ks * 16 + (lane >> 5) * 8;
    } else {
      int s2 = s - RGA * 4;
      int p = s2 / (RGB * 2);
      int rem = s2 % (RGB * 2);
      rg = rem >> 1; ks = rem & 1;
      plane = p ? Bl : Bh;
      poff = 2 * PLA + (p ? PLB : 0);
      int row = n0 + rg * 32 + (lane & 31);
      if (row >= N) row = N - 1;  // tail clamp (head GEMM); col-guarded store
      gsrc[t] = plane + (size_t)row * K + ks * 16 + (lane >> 5) * 8;
    }
    ldst[t] = poff + (rg * 2 + ks) * 512;
  }

  int wm = (wv >> 1) * (BM / 2), wn = (wv & 1) * (BN / 2);
  floatx16 acc[FI][FJ] = {};

  const short* As_h = lds;
  const short* As_l = lds + PLA;
  const short* Bs_h = lds + 2 * PLA;
  const short* Bs_l = lds + 2 * PLA + PLB;

  // prologue: stage k0=0
#pragma unroll
  for (int t = 0; t < SPW; ++t) gll16(gsrc[t], lds + ldst[t]);
#pragma unroll
  for (int t = 0; t < SPW; ++t) gsrc[t] += 32;

  for (int k0 = 0; k0 < K; k0 += 32) {
    __syncthreads();  // staged tile landed (vmcnt drained by compiler)
    // ds_read ALL fragments of this K-step into registers
    short8 ah[2][FI], alx[2][FI], bhx[2][FJ], blx[2][FJ];
#pragma unroll
    for (int ks = 0; ks < 2; ++ks) {
#pragma unroll
      for (int i = 0; i < FI; ++i) {
        int rg = (wm >> 5) + i;
        ah[ks][i]  = *(const short8*)(As_h + (rg * 2 + ks) * 512 + lane * 8);
        alx[ks][i] = *(const short8*)(As_l + (rg * 2 + ks) * 512 + lane * 8);
      }
#pragma unroll
      for (int j = 0; j < FJ; ++j) {
        int rg = (wn >> 5) + j;
        bhx[ks][j] = *(const short8*)(Bs_h + (rg * 2 + ks) * 512 + lane * 8);
        blx[ks][j] = *(const short8*)(Bs_l + (rg * 2 + ks) * 512 + lane * 8);
      }
    }
    __syncthreads();  // lgkm drained: frags in regs everywhere; LDS reusable
    if (k0 + 32 < K) {
#pragma unroll
      for (int t = 0; t < SPW; ++t) gll16(gsrc[t], lds + ldst[t]);
#pragma unroll
      for (int t = 0; t < SPW; ++t) gsrc[t] += 32;
    }
    __builtin_amdgcn_sched_barrier(0);  // keep load-issue before MFMA cluster
    __builtin_amdgcn_s_setprio(1);
#pragma unroll
    for (int ks = 0; ks < 2; ++ks)
#pragma unroll
      for (int i = 0; i < FI; ++i)
#pragma unroll
        for (int j = 0; j < FJ; ++j) {
          acc[i][j] = __builtin_amdgcn_mfma_f32_32x32x16_bf16(ah[ks][i], bhx[ks][j], acc[i][j], 0, 0, 0);
          acc[i][j] = __builtin_amdgcn_mfma_f32_32x32x16_bf16(ah[ks][i], blx[ks][j], acc[i][j], 0, 0, 0);
          acc[i][j] = __builtin_amdgcn_mfma_f32_32x32x16_bf16(alx[ks][i], bhx[ks][j], acc[i][j], 0, 0, 0);
        }
    __builtin_amdgcn_s_setprio(0);
  }

  // epilogue: 32x32 C/D layout col=lane&31, row=(r&3)+8*(r>>2)+4*(lane>>5)
  int cl = lane & 31, g2 = lane >> 5;
#pragma unroll
  for (int i = 0; i < FI; ++i) {
#pragma unroll
    for (int j = 0; j < FJ; ++j) {
      int col = n0 + wn + 32 * j + cl;
      if (col >= N) continue;
      floatx16 f = acc[i][j];
#pragma unroll
      for (int r = 0; r < 16; ++r) {
        int row = m0 + wm + 32 * i + (r & 3) + 8 * (r >> 2) + 4 * g2;
        float v = f[r];
        if (act == 1) {
          float hx = (v >= 0.f) ? v : 0.5f * v;
          v = hx * hx;
        }
        if (colscale) v *= colscale[col];
        size_t idx = (size_t)row * ldc + col;
        if (base) v += base[idx];
        if (Ch) {
          short hb = f2bf(v);
          Ch[idx] = hb;
          Cl[idx] = f2bf(v - bf2f(hb));
        } else {
          C[idx] = v;
        }
      }
    }
  }
}

__global__ __launch_bounds__(256, 3) void gemm_sb128(
    const short* __restrict__ Ah, const short* __restrict__ Al,
    const short* __restrict__ Bh, const short* __restrict__ Bl,
    float* __restrict__ C, short* __restrict__ Ch, short* __restrict__ Cl,
    const float* __restrict__ base, const float* __restrict__ colscale, int N,
    int K, int act) {
  __shared__ short lds[16384];  // 32 KiB
  int bx = blockIdx.x, by = blockIdx.y;
  xcd_swizzle(bx, by, gridDim.x, gridDim.y);
  gemm_sb_body<128, 128>(Ah, Al, Bh, Bl, C, Ch, Cl, base, colscale, bx * 128,
                         by * 128, N, N, K, act, lds);
}

__global__ __launch_bounds__(256, 4) void gemm_sb64(
    const short* __restrict__ Ah, const short* __restrict__ Al,
    const short* __restrict__ Bh, const short* __restrict__ Bl,
    float* __restrict__ C, const float* __restrict__ base,
    const float* __restrict__ colscale, int N, int K, int act) {
  __shared__ short lds[8192];  // 16 KiB
  int bx = blockIdx.x, by = blockIdx.y;
  xcd_swizzle(bx, by, gridDim.x, gridDim.y);
  gemm_sb_body<64, 64>(Ah, Al, Bh, Bl, C, nullptr, nullptr, base, colscale,
                       bx * 64, by * 64, N, N, K, act, lds);
}

// Fused q,k,v projection: grid (NTOK/64, 24). by<16 -> q, 16-19 -> k, 20-23 -> v.
__global__ __launch_bounds__(256, 4) void qkv_sb(
    const short* __restrict__ xnh, const short* __restrict__ xnl,
    const short* __restrict__ wqh, const short* __restrict__ wql,
    const short* __restrict__ wkh, const short* __restrict__ wkl,
    const short* __restrict__ wvh, const short* __restrict__ wvl,
    float* __restrict__ qb, float* __restrict__ kb, float* __restrict__ vb,
    const float* __restrict__ vemb, int K) {
  __shared__ short lds[8192];
  int bx = blockIdx.x, by = blockIdx.y;
  xcd_swizzle(bx, by, gridDim.x, gridDim.y);
  const short *Bh, *Bl;
  float* C;
  const float* base = nullptr;
  int n0, ldn;
  if (by < 16) {
    Bh = wqh; Bl = wql; C = qb; n0 = by * 64; ldn = Dc;
  } else if (by < 20) {
    Bh = wkh; Bl = wkl; C = kb; n0 = (by - 16) * 64; ldn = KVDc;
  } else {
    Bh = wvh; Bl = wvl; C = vb; base = vemb; n0 = (by - 20) * 64; ldn = KVDc;
  }
  gemm_sb_body<64, 64>(xnh, xnl, Bh, Bl, C, nullptr, nullptr, base, nullptr,
                       bx * 64, n0, ldn, ldn, K, 0, lds);
}

// ---------------------------------------------------------------------------
// QK head-RMS + RoPE (+q_gain). Block per token. (unchanged)
// ---------------------------------------------------------------------------
__global__ __launch_bounds__(256) void qkrope_kernel(
    float* __restrict__ q, float* __restrict__ k,
    const float* __restrict__ q_gain) {
  int bt = blockIdx.x;
  int t = bt % Tc;
  int tid = threadIdx.x;
  int lane = tid & 63, wv = tid >> 6;
  int fi = lane & 31;
  float inv = expf(-(float)(2 * fi) * (9.210340372f / 64.f));
  float ang = (float)t * inv;
  float cv = cosf(ang);
  float sv = sinf(ang);

#pragma unroll
  for (int hh = 0; hh < 4; ++hh) {
    int h = wv + hh * 4;
    float* qp = q + (size_t)bt * Dc + h * 64;
    float val = qp[lane];
    float ss = wave_sum(val * val);
    float rn = rsqrtf(ss / 64.f + 1e-6f);
    val *= rn;
    float partner = __shfl(val, lane ^ 32);
    float out = (lane < 32) ? (val * cv + partner * sv) : (val * cv - partner * sv);
    out *= q_gain[h];
    qp[lane] = out;
  }
  {
    int h = wv;
    float* kp = k + (size_t)bt * KVDc + h * 64;
    float val = kp[lane];
    float ss = wave_sum(val * val);
    float rn = rsqrtf(ss / 64.f + 1e-6f);
    val *= rn;
    float partner = __shfl(val, lane ^ 32);
    float out = (lane < 32) ? (val * cv + partner * sv) : (val * cv - partner * sv);
    kp[lane] = out;
  }
}

// ---------------------------------------------------------------------------
// K/V^T frag-order plane prep (unchanged).
// ---------------------------------------------------------------------------
__global__ __launch_bounds__(256) void kvprep_kernel(
    const float* __restrict__ kb, const float* __restrict__ vb,
    short* __restrict__ khG, short* __restrict__ klG,
    short* __restrict__ vthG, short* __restrict__ vtlG) {
  __shared__ float kf[64][65];
  __shared__ float vf[64][65];
  int kt = blockIdx.x, bh = blockIdx.y;
  int b = bh >> 2, hkv = bh & 3;
  int tid = threadIdx.x;
#pragma unroll
  for (int u = 0; u < 4; ++u) {
    int idx = tid + u * 256;  // 0..1023 float4 units
    int row = idx >> 4, c4 = idx & 15;
    size_t off = ((size_t)(b * Tc + kt * 64 + row)) * KVDc + hkv * 64 + c4 * 4;
    float4 k4 = *(const float4*)(kb + off);
    float4 v4 = *(const float4*)(vb + off);
    kf[row][c4 * 4 + 0] = k4.x; kf[row][c4 * 4 + 1] = k4.y;
    kf[row][c4 * 4 + 2] = k4.z; kf[row][c4 * 4 + 3] = k4.w;
    vf[row][c4 * 4 + 0] = v4.x; vf[row][c4 * 4 + 1] = v4.y;
    vf[row][c4 * 4 + 2] = v4.z; vf[row][c4 * 4 + 3] = v4.w;
  }
  __syncthreads();
  size_t gb = ((size_t)(bh * (Tc / 64) + kt)) * 4096;
#pragma unroll
  for (int u = 0; u < 2; ++u) {
    int unit = tid + u * 256;  // 0..511
    int s = unit >> 6, p = unit & 63;
    {  // K plane
      int half = s >> 2, rg = s & 3;
      int row = rg * 16 + (p & 15);
      int d0 = half * 32 + (p >> 4) * 8;
      short8 h8, l8;
#pragma unroll
      for (int e = 0; e < 8; ++e) {
        float v = kf[row][d0 + e];
        short hb = f2bf(v);
        h8[e] = hb;
        l8[e] = f2bf(v - bf2f(hb));
      }
      *(short8*)(khG + gb + s * 512 + p * 8) = h8;
      *(short8*)(klG + gb + s * 512 + p * 8) = l8;
    }
    {  // V^T plane
      int ks = s >> 2, jd = s & 3;
      int d = jd * 16 + (p & 15);
      int k0 = ks * 32 + (p >> 4) * 8;
      short8 h8, l8;
#pragma unroll
      for (int e = 0; e < 8; ++e) {
        float v = vf[k0 + e][d];
        short hb = f2bf(v);
        h8[e] = hb;
        l8[e] = f2bf(v - bf2f(hb));
      }
      *(short8*)(vthG + gb + s * 512 + p * 8) = h8;
      *(short8*)(vtlG + gb + s * 512 + p * 8) = l8;
    }
  }
}

// ---------------------------------------------------------------------------
// MFMA causal GQA flash attention + v-direction-removal epilogue.
// QBLK=16: grid (8, Tc/16); blockIdx.x = bh (one (b,hkv) per XCD -> K/V planes
// stay in that XCD's L2); qt = reversed blockIdx.y (heavy tiles first).
// 4 waves = 4 q-heads x 16 q-rows. LDS 48 KiB -> 3 blocks/CU.
// ---------------------------------------------------------------------------
__global__ __launch_bounds__(256) void attn_mfma(
    const float* __restrict__ qg_, const float* __restrict__ vg_,
    const short* __restrict__ khG, const short* __restrict__ klG,
    const short* __restrict__ vthG, const short* __restrict__ vtlG,
    short* __restrict__ yh_, short* __restrict__ yl_) {
  __shared__ short smem[24576];  // 48 KiB
  short* Khi  = smem;
  short* Klo  = smem + 4096;
  short* Vthi = smem + 8192;
  short* Vtlo = smem + 12288;

  int bh = blockIdx.x;                       // 0..7
  int qt = (gridDim.y - 1) - blockIdx.y;     // heavy first
  int b = bh >> 2, hkv = bh & 3;
  int tid = threadIdx.x;
  int lane = tid & 63, wv = tid >> 6;
  int x = lane & 15, g = lane >> 4;
  int h = hkv * 4 + wv;
  int qbase = qt * 16;

  short* PAhi = smem + 16384 + wv * 1024;
  short* PAlo = smem + 20480 + wv * 1024;

  short8 qh[2], qlo[2];  // [ks]
#pragma unroll
  for (int ks = 0; ks < 2; ++ks) {
    int qrow = qbase + x;
    const float* qp =
        qg_ + ((size_t)(b * Tc + qrow)) * Dc + h * 64 + ks * 32 + g * 8;
    float4 f0 = *(const float4*)qp;
    float4 f1 = *(const float4*)(qp + 4);
    float fv[8] = {f0.x, f0.y, f0.z, f0.w, f1.x, f1.y, f1.z, f1.w};
#pragma unroll
    for (int e = 0; e < 8; ++e) {
      short hb = f2bf(fv[e]);
      qh[ks][e] = hb;
      qlo[ks][e] = f2bf(fv[e] - bf2f(hb));
    }
  }

  // per-wave staging source (wave wv stages plane wv: Khi/Klo/Vthi/Vtlo)
  const short* planes[4] = {khG, klG, vthG, vtlG};
  const short* gplane = planes[wv] + ((size_t)bh * (Tc / 64)) * 4096 + lane * 8;
  short* lplane = smem + wv * 4096;

  floatx4 o[4] = {};
  float m_run = NEG_BIG, l_run = 0.f;

  int nkt = (qbase >> 6) + 1;
  for (int kt = 0; kt < nkt; ++kt) {
    const short* gs = gplane + (size_t)kt * 4096;
#pragma unroll
    for (int t = 0; t < 8; ++t) gll16(gs + t * 512, lplane + t * 512);
    __syncthreads();

    floatx4 st[4] = {};
#pragma unroll
    for (int ks = 0; ks < 2; ++ks) {
#pragma unroll
      for (int i = 0; i < 4; ++i) {
        short8 ka_h = *(const short8*)(Khi + ks * 2048 + i * 512 + lane * 8);
        short8 ka_l = *(const short8*)(Klo + ks * 2048 + i * 512 + lane * 8);
        st[i] = __builtin_amdgcn_mfma_f32_16x16x32_bf16(ka_h, qh[ks], st[i], 0, 0, 0);
        st[i] = __builtin_amdgcn_mfma_f32_16x16x32_bf16(ka_h, qlo[ks], st[i], 0, 0, 0);
        st[i] = __builtin_amdgcn_mfma_f32_16x16x32_bf16(ka_l, qh[ks], st[i], 0, 0, 0);
      }
    }

    // mask + online softmax (q column = qbase + x)
    float alv;
    {
      int qrow = qbase + x;
      float mx = NEG_BIG;
#pragma unroll
      for (int i = 0; i < 4; ++i) {
#pragma unroll
        for (int r = 0; r < 4; ++r) {
          int krow = kt * 64 + 16 * i + 4 * g + r;
          float s = st[i][r] * 0.125f;
          if (krow > qrow) s = NEG_BIG;
          st[i][r] = s;
          mx = fmaxf(mx, s);
        }
      }
      mx = fmaxf(mx, __shfl_xor(mx, 16));
      mx = fmaxf(mx, __shfl_xor(mx, 32));
      float m_new = fmaxf(m_run, mx);
      alv = __expf(m_run - m_new);
      float ts = 0.f;
#pragma unroll
      for (int i = 0; i < 4; ++i) {
#pragma unroll
        for (int r = 0; r < 4; ++r) {
          float p = __expf(st[i][r] - m_new);
          st[i][r] = p;
          ts += p;
        }
      }
      ts += __shfl_xor(ts, 16);
      ts += __shfl_xor(ts, 32);
      l_run = l_run * alv + ts;
      m_run = m_new;
    }

    // write P to per-wave LDS in A-frag order (hi/lo)
#pragma unroll
    for (int i = 0; i < 4; ++i) {
      short4v h4, l4;
#pragma unroll
      for (int r = 0; r < 4; ++r) {
        float p = st[i][r];
        short hb = f2bf(p);
        h4[r] = hb;
        l4[r] = f2bf(p - bf2f(hb));
      }
      int offp = (i >> 1) * 512 +
                 (x + (2 * (i & 1) + (g >> 1)) * 16) * 8 + 4 * (g & 1);
      *(short4v*)(PAhi + offp) = h4;
      *(short4v*)(PAlo + offp) = l4;
    }

    // rescale O by alpha (O rows q = 4g + r)
#pragma unroll
    for (int r = 0; r < 4; ++r) {
      float a = __shfl(alv, 4 * g + r);
#pragma unroll
      for (int jd = 0; jd < 4; ++jd) o[jd][r] *= a;
    }
    __syncthreads();

    // O += P · V
#pragma unroll
    for (int ks = 0; ks < 2; ++ks) {
      short8 pa_h = *(const short8*)(PAhi + ks * 512 + lane * 8);
      short8 pa_l = *(const short8*)(PAlo + ks * 512 + lane * 8);
#pragma unroll
      for (int jd = 0; jd < 4; ++jd) {
        short8 vb_h = *(const short8*)(Vthi + ks * 2048 + jd * 512 + lane * 8);
        short8 vb_l = *(const short8*)(Vtlo + ks * 2048 + jd * 512 + lane * 8);
        o[jd] = __builtin_amdgcn_mfma_f32_16x16x32_bf16(pa_h, vb_h, o[jd], 0, 0, 0);
        o[jd] = __builtin_amdgcn_mfma_f32_16x16x32_bf16(pa_h, vb_l, o[jd], 0, 0, 0);
        o[jd] = __builtin_amdgcn_mfma_f32_16x16x32_bf16(pa_l, vb_h, o[jd], 0, 0, 0);
      }
    }
    __syncthreads();
  }

  // finalize: /l_run, remove component along normalized v, store bf16 planes
#pragma unroll
  for (int r = 0; r < 4; ++r) {
    float lr = __shfl(l_run, 4 * g + r);
    float rcp = 1.f / lr;
    int qrow = qbase + 4 * g + r;
    const float* vr = vg_ + ((size_t)(b * Tc + qrow)) * KVDc + hkv * 64;
    float vv[4], oo[4];
    float pn = 0.f, pd = 0.f;
#pragma unroll
    for (int jd = 0; jd < 4; ++jd) {
      vv[jd] = vr[16 * jd + x];
      oo[jd] = o[jd][r] * rcp;
      pn += vv[jd] * vv[jd];
      pd += oo[jd] * vv[jd];
    }
#pragma unroll
    for (int off = 1; off <= 8; off <<= 1) {
      pn += __shfl_xor(pn, off);
      pd += __shfl_xor(pd, off);
    }
    float nrm = sqrtf(pn);
    float mxv = fmaxf(nrm, 1e-12f);
    float si = 1.f / mxv;
    float co = pd * si * si;
    size_t ybase = ((size_t)(b * Tc + qrow)) * Dc + h * 64;
#pragma unroll
    for (int jd = 0; jd < 4; ++jd) {
      float val = oo[jd] - co * vv[jd];
      short hb = f2bf(val);
      yh_[ybase + 16 * jd + x] = hb;
      yl_[ybase + 16 * jd + x] = f2bf(val - bf2f(hb));
    }
  }
}

// ---------------------------------------------------------------------------
extern "C" void kernel_launch(void* const* d_in, const int* in_sizes, int n_in,
                              void* d_out, int out_size, void* d_ws,
                              size_t ws_size, hipStream_t stream) {
  const int* ids          = (const int*)d_in[0];
  const float* embed_w    = (const float*)d_in[1];
  const float* big_w      = (const float*)d_in[2];
  const float* big_proj   = (const float*)d_in[3];
  const float* big_scale  = (const float*)d_in[4];
  const float* smear_gate = (const float*)d_in[5];
  const float* ve_w       = (const float*)d_in[6];
  const float* ve_proj    = (const float*)d_in[7];
  const float* ve_scale   = (const float*)d_in[8];
  const float* Wq         = (const float*)d_in[9];
  const float* Wk         = (const float*)d_in[10];
  const float* Wv         = (const float*)d_in[11];
  const float* Wo         = (const float*)d_in[12];
  const float* q_gain     = (const float*)d_in[13];
  const float* attn_scale = (const float*)d_in[14];
  const float* mlp_scale  = (const float*)d_in[15];
  const float* resid_mix  = (const float*)d_in[16];
  const float* Wfc        = (const float*)d_in[17];
  const float* Wp         = (const float*)d_in[18];
  const float* head_w     = (const float*)d_in[19];
  float* out = (float*)d_out;

  // ---- workspace layout ----
  char* p = (char*)d_ws;
  float* x     = (float*)p; p += SZ_X * 4;
  float* x0    = (float*)p; p += SZ_X * 4;
  float* x_in  = (float*)p; p += SZ_X * 4;
  float* qb    = (float*)p; p += SZ_X * 4;
  float* kb    = (float*)p; p += SZ_KV * 4;
  float* vb    = (float*)p; p += SZ_KV * 4;
  float* vemb  = (float*)p; p += SZ_KV * 4;
  float* raw_x = (float*)p; p += SZ_X * 4;
  short* xnh = (short*)p; p += SZ_X * 2;
  short* xnl = (short*)p; p += SZ_X * 2;
  short* yh  = (short*)p; p += SZ_X * 2;
  short* yl  = (short*)p; p += SZ_X * 2;
  short* hh  = (short*)p; p += SZ_H * 2;
  short* hl  = (short*)p; p += SZ_H * 2;
  short* khG  = (short*)p; p += SZ_KVP * 2;
  short* klG  = (short*)p; p += SZ_KVP * 2;
  short* vthG = (short*)p; p += SZ_KVP * 2;
  short* vtlG = (short*)p; p += SZ_KVP * 2;
  short* wqh = (short*)p; p += W_Q * 2;
  short* wql = (short*)p; p += W_Q * 2;
  short* wkh = (short*)p; p += W_KV * 2;
  short* wkl = (short*)p; p += W_KV * 2;
  short* wvh = (short*)p; p += W_KV * 2;
  short* wvl = (short*)p; p += W_KV * 2;
  short* woh = (short*)p; p += W_Q * 2;
  short* wol = (short*)p; p += W_Q * 2;
  short* wfh = (short*)p; p += W_FC * 2;
  short* wfl = (short*)p; p += W_FC * 2;
  short* wph = (short*)p; p += W_FC * 2;
  short* wpl = (short*)p; p += W_FC * 2;
  short* hwh = (short*)p; p += W_HD * 2;
  short* hwl = (short*)p; p += W_HD * 2;

  // ---- weight conversion (memory-bound) ----
  auto wc = [&](const float* s, short* h, short* l2, long n) {
    long n8 = n / 8;
    int blocks = (int)((n8 + 255) / 256);
    wcvt_kernel<<<blocks, 256, 0, stream>>>(s, h, l2, n8);
  };
  wc(Wq, wqh, wql, W_Q);
  wc(Wk, wkh, wkl, W_KV);
  wc(Wv, wvh, wvl, W_KV);
  wc(Wo, woh, wol, W_Q);
  wc(Wfc, wfh, wfl, W_FC);
  wc(Wp, wph, wpl, W_FC);
  wc(head_w, hwh, hwl, W_HD);

  embed_kernel<<<NTOK, 256, 0, stream>>>(ids, embed_w, big_w, big_proj,
                                         big_scale, ve_w, ve_proj, ve_scale,
                                         raw_x, vemb);
  smear_kernel<<<(int)(SZ_X / 256), 256, 0, stream>>>(raw_x, smear_gate, x, x0);

  for (int l = 0; l < Lc; ++l) {
    const float* mix = resid_mix + (size_t)l * 2 * Dc;
    prelayer_kernel<<<NTOK, 256, 0, stream>>>(x, x0, mix, x_in, xnh, xnl);
    // fused q,k,v projections (768 blocks)
    qkv_sb<<<dim3(NTOK / 64, 24), 256, 0, stream>>>(
        xnh, xnl, wqh + (size_t)l * Dc * Dc, wql + (size_t)l * Dc * Dc,
        wkh + (size_t)l * KVDc * Dc, wkl + (size_t)l * KVDc * Dc,
        wvh + (size_t)l * KVDc * Dc, wvl + (size_t)l * KVDc * Dc, qb, kb, vb,
        vemb, Dc);
    qkrope_kernel<<<NTOK, 256, 0, stream>>>(qb, kb, q_gain + (size_t)l * Hc);
    kvprep_kernel<<<dim3(Tc / 64, Bc * HKVc), 256, 0, stream>>>(
        kb, vb, khG, klG, vthG, vtlG);
    attn_mfma<<<dim3(Bc * HKVc, Tc / 16), 256, 0, stream>>>(
        qb, vb, khG, klG, vthG, vtlG, yh, yl);
    // out proj + residual: x = x_in + attn_scale * (y @ Wo.T)  (512 blocks)
    gemm_sb64<<<dim3(NTOK / 64, Dc / 64), 256, 0, stream>>>(
        yh, yl, woh + (size_t)l * Dc * Dc, wol + (size_t)l * Dc * Dc, x, x_in,
        attn_scale + (size_t)l * Dc, Dc, Dc, 0);
    // MLP
    rms_split_kernel<<<NTOK, 256, 0, stream>>>(x, xnh, xnl);
    gemm_sb128<<<dim3(NTOK / 128, MLPc / 128), 256, 0, stream>>>(
        xnh, xnl, wfh + (size_t)l * MLPc * Dc, wfl + (size_t)l * MLPc * Dc,
        nullptr, hh, hl, nullptr, nullptr, MLPc, Dc, 1);
    gemm_sb64<<<dim3(NTOK / 64, Dc / 64), 256, 0, stream>>>(
        hh, hl, wph + (size_t)l * Dc * MLPc, wpl + (size_t)l * Dc * MLPc, x, x,
        mlp_scale + (size_t)l * Dc, Dc, MLPc, 0);
  }

  rms_split_kernel<<<NTOK, 256, 0, stream>>>(x, xnh, xnl);
  gemm_sb128<<<dim3(NTOK / 128, (Vc + 127) / 128), 256, 0, stream>>>(
      xnh, xnl, hwh, hwl, out, nullptr, nullptr, nullptr, nullptr, Vc, Dc, 0);
}

// Round 7
// 5335.300 us; speedup vs baseline: 1.0855x; 1.0117x over previous
//
#include <hip/hip_runtime.h>
#include <hip/hip_bf16.h>

// Problem constants (match reference)
constexpr int Bc   = 2;
constexpr int Tc   = 1024;
constexpr int Vc   = 50257;
constexpr int Lc   = 8;
constexpr int Dc   = 1024;
constexpr int Hc   = 16;
constexpr int HKVc = 4;
constexpr int HDc  = 64;     // D/H
constexpr int KVDc = 256;    // HKV*HD
constexpr int MLPc = 4096;   // 4*D
constexpr int BVc  = 65536;
constexpr int BDc  = 256;
constexpr int VEDc = 128;

constexpr int NTOK = Bc * Tc;          // 2048
constexpr long SZ_X  = (long)NTOK * Dc;    // 2,097,152
constexpr long SZ_KV = (long)NTOK * KVDc;  // 524,288
constexpr long SZ_H  = (long)NTOK * MLPc;  // 8,388,608

constexpr long W_Q  = (long)Lc * Dc * Dc;     // 8,388,608
constexpr long W_KV = (long)Lc * KVDc * Dc;   // 2,097,152
constexpr long W_FC = (long)Lc * MLPc * Dc;   // 33,554,432
constexpr long W_HD = (long)Vc * Dc;          // 51,463,168
constexpr long SZ_KVP = (long)Bc * HKVc * (Tc / 64) * 4096;  // 524,288 shorts/plane

#define NEG_BIG (-3.0e38f)

typedef __attribute__((ext_vector_type(8))) short short8;    // 8 bf16 (4 VGPRs)
typedef __attribute__((ext_vector_type(4))) short short4v;   // 4 bf16 (8 B)
typedef __attribute__((ext_vector_type(4))) float floatx4;   // 16x16 MFMA acc
typedef __attribute__((ext_vector_type(16))) float floatx16; // 32x32 MFMA acc

__device__ __forceinline__ float wave_sum(float v) {
#pragma unroll
  for (int off = 32; off >= 1; off >>= 1) v += __shfl_xor(v, off);
  return v;
}

// Bijective XCD-aware swizzle (m204 formula).
__device__ __forceinline__ void xcd_swizzle(int& bx, int& by, int nbx, int nby) {
  int n = nbx * nby;
  int lin = by * nbx + bx;
  int q = n >> 3, rm = n & 7;
  int xcd = lin & 7, idx = lin >> 3;
  int v = (xcd < rm) ? (xcd * (q + 1) + idx)
                     : (rm * (q + 1) + (xcd - rm) * q + idx);
  bx = v % nbx;
  by = v / nbx;
}

// async global->LDS, 16B per lane. LDS dest = wave-uniform base + lane*16.
__device__ __forceinline__ void gll16(const void* g, void* l) {
  __builtin_amdgcn_global_load_lds(
      (const __attribute__((address_space(1))) unsigned int*)g,
      (__attribute__((address_space(3))) unsigned int*)l, 16, 0, 0);
}

// ---------------------------------------------------------------------------
// bf16 split helpers: f = bf2f(hi) + bf2f(lo) + O(2^-17 * f)
// ---------------------------------------------------------------------------
__device__ __forceinline__ short f2bf(float f) {
  unsigned u = __float_as_uint(f);
  return (short)((u + 0x7fffu + ((u >> 16) & 1u)) >> 16);
}
__device__ __forceinline__ float bf2f(short h) {
  return __uint_as_float(((unsigned)(unsigned short)h) << 16);
}

// ---------------------------------------------------------------------------
// Weight conversion: fp32 -> (hi, lo) bf16 planes. 8 elems/thread.
// ---------------------------------------------------------------------------
__global__ __launch_bounds__(256) void wcvt_kernel(
    const float* __restrict__ src, short* __restrict__ hi,
    short* __restrict__ lo, long n8) {
  long i = (long)blockIdx.x * 256 + threadIdx.x;
  if (i >= n8) return;
  const float* s = src + i * 8;
  float4 f0 = *(const float4*)s;
  float4 f1 = *(const float4*)(s + 4);
  float fv[8] = {f0.x, f0.y, f0.z, f0.w, f1.x, f1.y, f1.z, f1.w};
  short8 h8, l8;
#pragma unroll
  for (int e = 0; e < 8; ++e) {
    short hb = f2bf(fv[e]);
    h8[e] = hb;
    l8[e] = f2bf(fv[e] - bf2f(hb));
  }
  *(short8*)(hi + i * 8) = h8;
  *(short8*)(lo + i * 8) = l8;
}

// ---------------------------------------------------------------------------
// Embedding (unchanged)
// ---------------------------------------------------------------------------
__global__ __launch_bounds__(256) void embed_kernel(
    const int* __restrict__ ids, const float* __restrict__ embed_w,
    const float* __restrict__ big_w, const float* __restrict__ big_proj,
    const float* __restrict__ big_scale, const float* __restrict__ ve_w,
    const float* __restrict__ ve_proj, const float* __restrict__ ve_scale,
    float* __restrict__ raw_x, float* __restrict__ vemb) {
  int bt = blockIdx.x;
  int tid = threadIdx.x;
  int t = bt % Tc;
  int tok = ids[bt];

  const float* e = embed_w + (size_t)tok * Dc;
  float ev[4];
  float ss = 0.f;
#pragma unroll
  for (int i = 0; i < 4; ++i) {
    ev[i] = e[tid + i * 256];
    ss += ev[i] * ev[i];
  }
  __shared__ float red[4];
  __shared__ float brow[BDc];
  __shared__ float verow[VEDc];
  float wsum = wave_sum(ss);
  if ((tid & 63) == 0) red[tid >> 6] = wsum;

  int bg;
  if (t == 0) {
    bg = BVc - 1;
  } else {
    unsigned a = (unsigned)ids[bt];
    unsigned p = (unsigned)ids[bt - 1];
    bg = (int)(((36313u * a) ^ (27191u * p)) % 65535u);
  }
  brow[tid] = big_w[(size_t)bg * BDc + tid];
  if (tid < VEDc) verow[tid] = ve_w[(size_t)tok * VEDc + tid];
  __syncthreads();

  float tot = red[0] + red[1] + red[2] + red[3];
  float rn = rsqrtf(tot / (float)Dc + 1e-6f);
  float bs = big_scale[0];
#pragma unroll
  for (int i = 0; i < 4; ++i) {
    int d = tid + i * 256;
    const float* bp = big_proj + (size_t)d * BDc;
    float dot = 0.f;
    for (int c = 0; c < BDc; ++c) dot += brow[c] * bp[c];
    raw_x[(size_t)bt * Dc + d] = ev[i] * rn + dot * bs;
  }
  {
    float vs = ve_scale[0];
    int d = tid;
    const float* vp = ve_proj + (size_t)d * VEDc;
    float dot = 0.f;
    for (int c = 0; c < VEDc; ++c) dot += verow[c] * vp[c];
    vemb[(size_t)bt * KVDc + d] = dot * vs;
  }
}

// ---------------------------------------------------------------------------
// Smear (unchanged)
// ---------------------------------------------------------------------------
__global__ __launch_bounds__(256) void smear_kernel(
    const float* __restrict__ raw, const float* __restrict__ gate,
    float* __restrict__ x, float* __restrict__ x0) {
  long idx = (long)blockIdx.x * 256 + threadIdx.x;
  if (idx >= SZ_X) return;
  int d = (int)(idx & (Dc - 1));
  int t = (int)((idx / Dc) & (Tc - 1));
  float g = 1.f / (1.f + expf(-gate[d]));
  float cur = raw[idx];
  float prev = (t > 0) ? raw[idx - Dc] : 0.f;
  float val = (1.f - g) * cur + g * prev;
  x[idx] = val;
  x0[idx] = val;
}

// ---------------------------------------------------------------------------
// Pre-layer: x_in = mix0*x + mix1*x0 ; xn planes = split(rms(x_in)).
// ---------------------------------------------------------------------------
__global__ __launch_bounds__(256) void prelayer_kernel(
    const float* __restrict__ x, const float* __restrict__ x0,
    const float* __restrict__ mix, float* __restrict__ x_in,
    short* __restrict__ xnh, short* __restrict__ xnl) {
  int bt = blockIdx.x;
  int tid = threadIdx.x;
  const float* xr = x + (size_t)bt * Dc;
  const float* x0r = x0 + (size_t)bt * Dc;
  float vals[4];
  float ss = 0.f;
#pragma unroll
  for (int i = 0; i < 4; ++i) {
    int d = tid + i * 256;
    float v = mix[d] * xr[d] + mix[Dc + d] * x0r[d];
    vals[i] = v;
    ss += v * v;
  }
  __shared__ float red[4];
  float wsum = wave_sum(ss);
  if ((tid & 63) == 0) red[tid >> 6] = wsum;
  __syncthreads();
  float tot = red[0] + red[1] + red[2] + red[3];
  float rn = rsqrtf(tot / (float)Dc + 1e-6f);
#pragma unroll
  for (int i = 0; i < 4; ++i) {
    int d = tid + i * 256;
    size_t idx = (size_t)bt * Dc + d;
    x_in[idx] = vals[i];
    float vn = vals[i] * rn;
    short hb = f2bf(vn);
    xnh[idx] = hb;
    xnl[idx] = f2bf(vn - bf2f(hb));
  }
}

// ---------------------------------------------------------------------------
// RMS over D -> bf16 hi/lo planes. Block per token.
// ---------------------------------------------------------------------------
__global__ __launch_bounds__(256) void rms_split_kernel(
    const float* __restrict__ in, short* __restrict__ oh,
    short* __restrict__ ol) {
  int bt = blockIdx.x;
  int tid = threadIdx.x;
  const float* p = in + (size_t)bt * Dc;
  float v[4];
  float ss = 0.f;
#pragma unroll
  for (int i = 0; i < 4; ++i) {
    v[i] = p[tid + i * 256];
    ss += v[i] * v[i];
  }
  __shared__ float red[4];
  float wsum = wave_sum(ss);
  if ((tid & 63) == 0) red[tid >> 6] = wsum;
  __syncthreads();
  float tot = red[0] + red[1] + red[2] + red[3];
  float rn = rsqrtf(tot / (float)Dc + 1e-6f);
#pragma unroll
  for (int i = 0; i < 4; ++i) {
    size_t idx = (size_t)bt * Dc + tid + i * 256;
    float vn = v[i] * rn;
    short hb = f2bf(vn);
    oh[idx] = hb;
    ol[idx] = f2bf(vn - bf2f(hb));
  }
}

// ---------------------------------------------------------------------------
// Double-buffered plane GEMM body with COUNTED vmcnt pipeline (T3+T4):
//   prologue stages tiles 0,1. Per step s:
//     vmcnt(SPW) [tile s landed; s+1 in flight] -> s_barrier
//     ds_read all frags -> lgkmcnt(0) -> s_barrier [buffer free]
//     issue tile s+2 into freed buffer -> setprio(1) MFMA cluster setprio(0)
//   Never drains vmcnt to 0 mid-loop; loads get ~2 iterations to land.
// Tile BM x BN, BK=32, 4 waves (2x2), wave tile (BM/2) x (BN/2), 32x32x16.
// LDS frag order: subtile (rg,ks) = 32 rows x 16 k at (rg*2+ks)*1024B,
// lane l -> l*16B (row l&31, k-octet l>>5) => conflict-free b128, zero cvt.
// ---------------------------------------------------------------------------
template <int BM, int BN>
__device__ __forceinline__ void gemm_db_body(
    const short* __restrict__ Ah, const short* __restrict__ Al,
    const short* __restrict__ Bh, const short* __restrict__ Bl,
    float* __restrict__ C, short* __restrict__ Ch, short* __restrict__ Cl,
    const float* __restrict__ base, const float* __restrict__ colscale,
    int m0, int n0, int N, int ldc, int K, int act, short* lds) {
  constexpr int RGA = BM / 32;
  constexpr int RGB = BN / 32;
  constexpr int SPW = RGA + RGB;        // gll16 per wave per stage
  constexpr int PLA = RGA * 1024;       // shorts per A plane
  constexpr int PLB = RGB * 1024;
  constexpr int HB = 2 * (PLA + PLB);   // shorts per buffer
  constexpr int FI = BM / 64;
  constexpr int FJ = BN / 64;

  int tid = threadIdx.x, lane = tid & 63, wv = tid >> 6;

  const short* gsrc[SPW];
  int ldst[SPW];
#pragma unroll
  for (int t = 0; t < SPW; ++t) {
    int s = wv * SPW + t;
    const short* plane;
    int poff, rg, ks;
    if (s < RGA * 4) {
      int p = s / (RGA * 2);
      int rem = s % (RGA * 2);
      rg = rem >> 1; ks = rem & 1;
      plane = p ? Al : Ah;
      poff = p ? PLA : 0;
      int row = m0 + rg * 32 + (lane & 31);
      gsrc[t] = plane + (size_t)row * K + ks * 16 + (lane >> 5) * 8;
    } else {
      int s2 = s - RGA * 4;
      int p = s2 / (RGB * 2);
      int rem = s2 % (RGB * 2);
      rg = rem >> 1; ks = rem & 1;
      plane = p ? Bl : Bh;
      poff = 2 * PLA + (p ? PLB : 0);
      int row = n0 + rg * 32 + (lane & 31);
      if (row >= N) row = N - 1;  // tail clamp (head GEMM); col-guarded store
      gsrc[t] = plane + (size_t)row * K + ks * 16 + (lane >> 5) * 8;
    }
    ldst[t] = poff + (rg * 2 + ks) * 512;
  }

  int wm = (wv >> 1) * (BM / 2), wn = (wv & 1) * (BN / 2);
  floatx16 acc[FI][FJ] = {};

  // prologue: stage tile 0 -> buf0, tile 1 -> buf1 (K >= 64 always here)
#pragma unroll
  for (int t = 0; t < SPW; ++t) gll16(gsrc[t], lds + ldst[t]);
#pragma unroll
  for (int t = 0; t < SPW; ++t) gsrc[t] += 32;
#pragma unroll
  for (int t = 0; t < SPW; ++t) gll16(gsrc[t], lds + HB + ldst[t]);
#pragma unroll
  for (int t = 0; t < SPW; ++t) gsrc[t] += 32;

  int cur = 0;
  for (int k0 = 0; k0 < K; k0 += 32) {
    // tile-k landed (its SPW loads are this wave's oldest); tile k+1 in flight
    if (k0 + 32 < K) {
      if constexpr (SPW == 8) {
        asm volatile("s_waitcnt vmcnt(8)" ::: "memory");
      } else {
        asm volatile("s_waitcnt vmcnt(4)" ::: "memory");
      }
    } else {
      asm volatile("s_waitcnt vmcnt(0)" ::: "memory");
    }
    __builtin_amdgcn_s_barrier();
    __builtin_amdgcn_sched_barrier(0);

    const short* As_h = lds + cur * HB;
    const short* As_l = As_h + PLA;
    const short* Bs_h = As_h + 2 * PLA;
    const short* Bs_l = Bs_h + PLB;
    short8 ah[2][FI], alx[2][FI], bhx[2][FJ], blx[2][FJ];
#pragma unroll
    for (int ks = 0; ks < 2; ++ks) {
#pragma unroll
      for (int i = 0; i < FI; ++i) {
        int rg = (wm >> 5) + i;
        ah[ks][i]  = *(const short8*)(As_h + (rg * 2 + ks) * 512 + lane * 8);
        alx[ks][i] = *(const short8*)(As_l + (rg * 2 + ks) * 512 + lane * 8);
      }
#pragma unroll
      for (int j = 0; j < FJ; ++j) {
        int rg = (wn >> 5) + j;
        bhx[ks][j] = *(const short8*)(Bs_h + (rg * 2 + ks) * 512 + lane * 8);
        blx[ks][j] = *(const short8*)(Bs_l + (rg * 2 + ks) * 512 + lane * 8);
      }
    }
    asm volatile("s_waitcnt lgkmcnt(0)" ::: "memory");
    __builtin_amdgcn_sched_barrier(0);
    __builtin_amdgcn_s_barrier();  // all waves done reading buf[cur]

    if (k0 + 64 < K) {  // stage tile k+2 into the freed buffer
#pragma unroll
      for (int t = 0; t < SPW; ++t) gll16(gsrc[t], lds + cur * HB + ldst[t]);
#pragma unroll
      for (int t = 0; t < SPW; ++t) gsrc[t] += 32;
    }
    __builtin_amdgcn_sched_barrier(0);  // loads issued before MFMA cluster

    __builtin_amdgcn_s_setprio(1);
    // pass-major order: consecutive MFMAs hit different accumulators
#pragma unroll
    for (int ks = 0; ks < 2; ++ks) {
#pragma unroll
      for (int i = 0; i < FI; ++i)
#pragma unroll
        for (int j = 0; j < FJ; ++j)
          acc[i][j] = __builtin_amdgcn_mfma_f32_32x32x16_bf16(ah[ks][i], bhx[ks][j], acc[i][j], 0, 0, 0);
#pragma unroll
      for (int i = 0; i < FI; ++i)
#pragma unroll
        for (int j = 0; j < FJ; ++j)
          acc[i][j] = __builtin_amdgcn_mfma_f32_32x32x16_bf16(ah[ks][i], blx[ks][j], acc[i][j], 0, 0, 0);
#pragma unroll
      for (int i = 0; i < FI; ++i)
#pragma unroll
        for (int j = 0; j < FJ; ++j)
          acc[i][j] = __builtin_amdgcn_mfma_f32_32x32x16_bf16(alx[ks][i], bhx[ks][j], acc[i][j], 0, 0, 0);
    }
    __builtin_amdgcn_s_setprio(0);
    cur ^= 1;
  }

  // epilogue: 32x32 C/D layout col=lane&31, row=(r&3)+8*(r>>2)+4*(lane>>5)
  int cl = lane & 31, g2 = lane >> 5;
#pragma unroll
  for (int i = 0; i < FI; ++i) {
#pragma unroll
    for (int j = 0; j < FJ; ++j) {
      int col = n0 + wn + 32 * j + cl;
      if (col >= N) continue;
      floatx16 f = acc[i][j];
#pragma unroll
      for (int r = 0; r < 16; ++r) {
        int row = m0 + wm + 32 * i + (r & 3) + 8 * (r >> 2) + 4 * g2;
        float v = f[r];
        if (act == 1) {
          float hx = (v >= 0.f) ? v : 0.5f * v;
          v = hx * hx;
        }
        if (colscale) v *= colscale[col];
        size_t idx = (size_t)row * ldc + col;
        if (base) v += base[idx];
        if (Ch) {
          short hb = f2bf(v);
          Ch[idx] = hb;
          Cl[idx] = f2bf(v - bf2f(hb));
        } else {
          C[idx] = v;
        }
      }
    }
  }
}

__global__ __launch_bounds__(256, 2) void gemm_sb128(
    const short* __restrict__ Ah, const short* __restrict__ Al,
    const short* __restrict__ Bh, const short* __restrict__ Bl,
    float* __restrict__ C, short* __restrict__ Ch, short* __restrict__ Cl,
    const float* __restrict__ base, const float* __restrict__ colscale, int N,
    int K, int act) {
  __shared__ short lds[32768];  // 64 KiB: 2 buffers
  int bx = blockIdx.x, by = blockIdx.y;
  xcd_swizzle(bx, by, gridDim.x, gridDim.y);
  gemm_db_body<128, 128>(Ah, Al, Bh, Bl, C, Ch, Cl, base, colscale, bx * 128,
                         by * 128, N, N, K, act, lds);
}

__global__ __launch_bounds__(256, 4) void gemm_sb64(
    const short* __restrict__ Ah, const short* __restrict__ Al,
    const short* __restrict__ Bh, const short* __restrict__ Bl,
    float* __restrict__ C, const float* __restrict__ base,
    const float* __restrict__ colscale, int N, int K, int act) {
  __shared__ short lds[16384];  // 32 KiB: 2 buffers
  int bx = blockIdx.x, by = blockIdx.y;
  xcd_swizzle(bx, by, gridDim.x, gridDim.y);
  gemm_db_body<64, 64>(Ah, Al, Bh, Bl, C, nullptr, nullptr, base, colscale,
                       bx * 64, by * 64, N, N, K, act, lds);
}

// Fused q,k,v projection: grid (NTOK/64, 24). by<16 -> q, 16-19 -> k, 20-23 -> v.
__global__ __launch_bounds__(256, 4) void qkv_sb(
    const short* __restrict__ xnh, const short* __restrict__ xnl,
    const short* __restrict__ wqh, const short* __restrict__ wql,
    const short* __restrict__ wkh, const short* __restrict__ wkl,
    const short* __restrict__ wvh, const short* __restrict__ wvl,
    float* __restrict__ qb, float* __restrict__ kb, float* __restrict__ vb,
    const float* __restrict__ vemb, int K) {
  __shared__ short lds[16384];
  int bx = blockIdx.x, by = blockIdx.y;
  xcd_swizzle(bx, by, gridDim.x, gridDim.y);
  const short *Bh, *Bl;
  float* C;
  const float* base = nullptr;
  int n0, ldn;
  if (by < 16) {
    Bh = wqh; Bl = wql; C = qb; n0 = by * 64; ldn = Dc;
  } else if (by < 20) {
    Bh = wkh; Bl = wkl; C = kb; n0 = (by - 16) * 64; ldn = KVDc;
  } else {
    Bh = wvh; Bl = wvl; C = vb; base = vemb; n0 = (by - 20) * 64; ldn = KVDc;
  }
  gemm_db_body<64, 64>(xnh, xnl, Bh, Bl, C, nullptr, nullptr, base, nullptr,
                       bx * 64, n0, ldn, ldn, K, 0, lds);
}

// ---------------------------------------------------------------------------
// QK head-RMS + RoPE (+q_gain). Block per token. (unchanged)
// ---------------------------------------------------------------------------
__global__ __launch_bounds__(256) void qkrope_kernel(
    float* __restrict__ q, float* __restrict__ k,
    const float* __restrict__ q_gain) {
  int bt = blockIdx.x;
  int t = bt % Tc;
  int tid = threadIdx.x;
  int lane = tid & 63, wv = tid >> 6;
  int fi = lane & 31;
  float inv = expf(-(float)(2 * fi) * (9.210340372f / 64.f));
  float ang = (float)t * inv;
  float cv = cosf(ang);
  float sv = sinf(ang);

#pragma unroll
  for (int hh = 0; hh < 4; ++hh) {
    int h = wv + hh * 4;
    float* qp = q + (size_t)bt * Dc + h * 64;
    float val = qp[lane];
    float ss = wave_sum(val * val);
    float rn = rsqrtf(ss / 64.f + 1e-6f);
    val *= rn;
    float partner = __shfl(val, lane ^ 32);
    float out = (lane < 32) ? (val * cv + partner * sv) : (val * cv - partner * sv);
    out *= q_gain[h];
    qp[lane] = out;
  }
  {
    int h = wv;
    float* kp = k + (size_t)bt * KVDc + h * 64;
    float val = kp[lane];
    float ss = wave_sum(val * val);
    float rn = rsqrtf(ss / 64.f + 1e-6f);
    val *= rn;
    float partner = __shfl(val, lane ^ 32);
    float out = (lane < 32) ? (val * cv + partner * sv) : (val * cv - partner * sv);
    kp[lane] = out;
  }
}

// ---------------------------------------------------------------------------
// K/V^T frag-order plane prep (unchanged).
// ---------------------------------------------------------------------------
__global__ __launch_bounds__(256) void kvprep_kernel(
    const float* __restrict__ kb, const float* __restrict__ vb,
    short* __restrict__ khG, short* __restrict__ klG,
    short* __restrict__ vthG, short* __restrict__ vtlG) {
  __shared__ float kf[64][65];
  __shared__ float vf[64][65];
  int kt = blockIdx.x, bh = blockIdx.y;
  int b = bh >> 2, hkv = bh & 3;
  int tid = threadIdx.x;
#pragma unroll
  for (int u = 0; u < 4; ++u) {
    int idx = tid + u * 256;  // 0..1023 float4 units
    int row = idx >> 4, c4 = idx & 15;
    size_t off = ((size_t)(b * Tc + kt * 64 + row)) * KVDc + hkv * 64 + c4 * 4;
    float4 k4 = *(const float4*)(kb + off);
    float4 v4 = *(const float4*)(vb + off);
    kf[row][c4 * 4 + 0] = k4.x; kf[row][c4 * 4 + 1] = k4.y;
    kf[row][c4 * 4 + 2] = k4.z; kf[row][c4 * 4 + 3] = k4.w;
    vf[row][c4 * 4 + 0] = v4.x; vf[row][c4 * 4 + 1] = v4.y;
    vf[row][c4 * 4 + 2] = v4.z; vf[row][c4 * 4 + 3] = v4.w;
  }
  __syncthreads();
  size_t gb = ((size_t)(bh * (Tc / 64) + kt)) * 4096;
#pragma unroll
  for (int u = 0; u < 2; ++u) {
    int unit = tid + u * 256;  // 0..511
    int s = unit >> 6, p = unit & 63;
    {  // K plane
      int half = s >> 2, rg = s & 3;
      int row = rg * 16 + (p & 15);
      int d0 = half * 32 + (p >> 4) * 8;
      short8 h8, l8;
#pragma unroll
      for (int e = 0; e < 8; ++e) {
        float v = kf[row][d0 + e];
        short hb = f2bf(v);
        h8[e] = hb;
        l8[e] = f2bf(v - bf2f(hb));
      }
      *(short8*)(khG + gb + s * 512 + p * 8) = h8;
      *(short8*)(klG + gb + s * 512 + p * 8) = l8;
    }
    {  // V^T plane
      int ks = s >> 2, jd = s & 3;
      int d = jd * 16 + (p & 15);
      int k0 = ks * 32 + (p >> 4) * 8;
      short8 h8, l8;
#pragma unroll
      for (int e = 0; e < 8; ++e) {
        float v = vf[k0 + e][d];
        short hb = f2bf(v);
        h8[e] = hb;
        l8[e] = f2bf(v - bf2f(hb));
      }
      *(short8*)(vthG + gb + s * 512 + p * 8) = h8;
      *(short8*)(vtlG + gb + s * 512 + p * 8) = l8;
    }
  }
}

// ---------------------------------------------------------------------------
// MFMA causal GQA flash attention + v-direction-removal epilogue (unchanged).
// ---------------------------------------------------------------------------
__global__ __launch_bounds__(256) void attn_mfma(
    const float* __restrict__ qg_, const float* __restrict__ vg_,
    const short* __restrict__ khG, const short* __restrict__ klG,
    const short* __restrict__ vthG, const short* __restrict__ vtlG,
    short* __restrict__ yh_, short* __restrict__ yl_) {
  __shared__ short smem[24576];  // 48 KiB
  short* Khi  = smem;
  short* Klo  = smem + 4096;
  short* Vthi = smem + 8192;
  short* Vtlo = smem + 12288;

  int bh = blockIdx.x;                       // 0..7
  int qt = (gridDim.y - 1) - blockIdx.y;     // heavy first
  int b = bh >> 2, hkv = bh & 3;
  int tid = threadIdx.x;
  int lane = tid & 63, wv = tid >> 6;
  int x = lane & 15, g = lane >> 4;
  int h = hkv * 4 + wv;
  int qbase = qt * 16;

  short* PAhi = smem + 16384 + wv * 1024;
  short* PAlo = smem + 20480 + wv * 1024;

  short8 qh[2], qlo[2];  // [ks]
#pragma unroll
  for (int ks = 0; ks < 2; ++ks) {
    int qrow = qbase + x;
    const float* qp =
        qg_ + ((size_t)(b * Tc + qrow)) * Dc + h * 64 + ks * 32 + g * 8;
    float4 f0 = *(const float4*)qp;
    float4 f1 = *(const float4*)(qp + 4);
    float fv[8] = {f0.x, f0.y, f0.z, f0.w, f1.x, f1.y, f1.z, f1.w};
#pragma unroll
    for (int e = 0; e < 8; ++e) {
      short hb = f2bf(fv[e]);
      qh[ks][e] = hb;
      qlo[ks][e] = f2bf(fv[e] - bf2f(hb));
    }
  }

  // per-wave staging source (wave wv stages plane wv: Khi/Klo/Vthi/Vtlo)
  const short* planes[4] = {khG, klG, vthG, vtlG};
  const short* gplane = planes[wv] + ((size_t)bh * (Tc / 64)) * 4096 + lane * 8;
  short* lplane = smem + wv * 4096;

  floatx4 o[4] = {};
  float m_run = NEG_BIG, l_run = 0.f;

  int nkt = (qbase >> 6) + 1;
  for (int kt = 0; kt < nkt; ++kt) {
    const short* gs = gplane + (size_t)kt * 4096;
#pragma unroll
    for (int t = 0; t < 8; ++t) gll16(gs + t * 512, lplane + t * 512);
    __syncthreads();

    floatx4 st[4] = {};
#pragma unroll
    for (int ks = 0; ks < 2; ++ks) {
#pragma unroll
      for (int i = 0; i < 4; ++i) {
        short8 ka_h = *(const short8*)(Khi + ks * 2048 + i * 512 + lane * 8);
        short8 ka_l = *(const short8*)(Klo + ks * 2048 + i * 512 + lane * 8);
        st[i] = __builtin_amdgcn_mfma_f32_16x16x32_bf16(ka_h, qh[ks], st[i], 0, 0, 0);
        st[i] = __builtin_amdgcn_mfma_f32_16x16x32_bf16(ka_h, qlo[ks], st[i], 0, 0, 0);
        st[i] = __builtin_amdgcn_mfma_f32_16x16x32_bf16(ka_l, qh[ks], st[i], 0, 0, 0);
      }
    }

    // mask + online softmax (q column = qbase + x)
    float alv;
    {
      int qrow = qbase + x;
      float mx = NEG_BIG;
#pragma unroll
      for (int i = 0; i < 4; ++i) {
#pragma unroll
        for (int r = 0; r < 4; ++r) {
          int krow = kt * 64 + 16 * i + 4 * g + r;
          float s = st[i][r] * 0.125f;
          if (krow > qrow) s = NEG_BIG;
          st[i][r] = s;
          mx = fmaxf(mx, s);
        }
      }
      mx = fmaxf(mx, __shfl_xor(mx, 16));
      mx = fmaxf(mx, __shfl_xor(mx, 32));
      float m_new = fmaxf(m_run, mx);
      alv = __expf(m_run - m_new);
      float ts = 0.f;
#pragma unroll
      for (int i = 0; i < 4; ++i) {
#pragma unroll
        for (int r = 0; r < 4; ++r) {
          float p = __expf(st[i][r] - m_new);
          st[i][r] = p;
          ts += p;
        }
      }
      ts += __shfl_xor(ts, 16);
      ts += __shfl_xor(ts, 32);
      l_run = l_run * alv + ts;
      m_run = m_new;
    }

    // write P to per-wave LDS in A-frag order (hi/lo)
#pragma unroll
    for (int i = 0; i < 4; ++i) {
      short4v h4, l4;
#pragma unroll
      for (int r = 0; r < 4; ++r) {
        float p = st[i][r];
        short hb = f2bf(p);
        h4[r] = hb;
        l4[r] = f2bf(p - bf2f(hb));
      }
      int offp = (i >> 1) * 512 +
                 (x + (2 * (i & 1) + (g >> 1)) * 16) * 8 + 4 * (g & 1);
      *(short4v*)(PAhi + offp) = h4;
      *(short4v*)(PAlo + offp) = l4;
    }

    // rescale O by alpha (O rows q = 4g + r)
#pragma unroll
    for (int r = 0; r < 4; ++r) {
      float a = __shfl(alv, 4 * g + r);
#pragma unroll
      for (int jd = 0; jd < 4; ++jd) o[jd][r] *= a;
    }
    __syncthreads();

    // O += P · V
#pragma unroll
    for (int ks = 0; ks < 2; ++ks) {
      short8 pa_h = *(const short8*)(PAhi + ks * 512 + lane * 8);
      short8 pa_l = *(const short8*)(PAlo + ks * 512 + lane * 8);
#pragma unroll
      for (int jd = 0; jd < 4; ++jd) {
        short8 vb_h = *(const short8*)(Vthi + ks * 2048 + jd * 512 + lane * 8);
        short8 vb_l = *(const short8*)(Vtlo + ks * 2048 + jd * 512 + lane * 8);
        o[jd] = __builtin_amdgcn_mfma_f32_16x16x32_bf16(pa_h, vb_h, o[jd], 0, 0, 0);
        o[jd] = __builtin_amdgcn_mfma_f32_16x16x32_bf16(pa_h, vb_l, o[jd], 0, 0, 0);
        o[jd] = __builtin_amdgcn_mfma_f32_16x16x32_bf16(pa_l, vb_h, o[jd], 0, 0, 0);
      }
    }
    __syncthreads();
  }

  // finalize: /l_run, remove component along normalized v, store bf16 planes
#pragma unroll
  for (int r = 0; r < 4; ++r) {
    float lr = __shfl(l_run, 4 * g + r);
    float rcp = 1.f / lr;
    int qrow = qbase + 4 * g + r;
    const float* vr = vg_ + ((size_t)(b * Tc + qrow)) * KVDc + hkv * 64;
    float vv[4], oo[4];
    float pn = 0.f, pd = 0.f;
#pragma unroll
    for (int jd = 0; jd < 4; ++jd) {
      vv[jd] = vr[16 * jd + x];
      oo[jd] = o[jd][r] * rcp;
      pn += vv[jd] * vv[jd];
      pd += oo[jd] * vv[jd];
    }
#pragma unroll
    for (int off = 1; off <= 8; off <<= 1) {
      pn += __shfl_xor(pn, off);
      pd += __shfl_xor(pd, off);
    }
    float nrm = sqrtf(pn);
    float mxv = fmaxf(nrm, 1e-12f);
    float si = 1.f / mxv;
    float co = pd * si * si;
    size_t ybase = ((size_t)(b * Tc + qrow)) * Dc + h * 64;
#pragma unroll
    for (int jd = 0; jd < 4; ++jd) {
      float val = oo[jd] - co * vv[jd];
      short hb = f2bf(val);
      yh_[ybase + 16 * jd + x] = hb;
      yl_[ybase + 16 * jd + x] = f2bf(val - bf2f(hb));
    }
  }
}

// ---------------------------------------------------------------------------
extern "C" void kernel_launch(void* const* d_in, const int* in_sizes, int n_in,
                              void* d_out, int out_size, void* d_ws,
                              size_t ws_size, hipStream_t stream) {
  const int* ids          = (const int*)d_in[0];
  const float* embed_w    = (const float*)d_in[1];
  const float* big_w      = (const float*)d_in[2];
  const float* big_proj   = (const float*)d_in[3];
  const float* big_scale  = (const float*)d_in[4];
  const float* smear_gate = (const float*)d_in[5];
  const float* ve_w       = (const float*)d_in[6];
  const float* ve_proj    = (const float*)d_in[7];
  const float* ve_scale   = (const float*)d_in[8];
  const float* Wq         = (const float*)d_in[9];
  const float* Wk         = (const float*)d_in[10];
  const float* Wv         = (const float*)d_in[11];
  const float* Wo         = (const float*)d_in[12];
  const float* q_gain     = (const float*)d_in[13];
  const float* attn_scale = (const float*)d_in[14];
  const float* mlp_scale  = (const float*)d_in[15];
  const float* resid_mix  = (const float*)d_in[16];
  const float* Wfc        = (const float*)d_in[17];
  const float* Wp         = (const float*)d_in[18];
  const float* head_w     = (const float*)d_in[19];
  float* out = (float*)d_out;

  // ---- workspace layout ----
  char* p = (char*)d_ws;
  float* x     = (float*)p; p += SZ_X * 4;
  float* x0    = (float*)p; p += SZ_X * 4;
  float* x_in  = (float*)p; p += SZ_X * 4;
  float* qb    = (float*)p; p += SZ_X * 4;
  float* kb    = (float*)p; p += SZ_KV * 4;
  float* vb    = (float*)p; p += SZ_KV * 4;
  float* vemb  = (float*)p; p += SZ_KV * 4;
  float* raw_x = (float*)p; p += SZ_X * 4;
  short* xnh = (short*)p; p += SZ_X * 2;
  short* xnl = (short*)p; p += SZ_X * 2;
  short* yh  = (short*)p; p += SZ_X * 2;
  short* yl  = (short*)p; p += SZ_X * 2;
  short* hh  = (short*)p; p += SZ_H * 2;
  short* hl  = (short*)p; p += SZ_H * 2;
  short* khG  = (short*)p; p += SZ_KVP * 2;
  short* klG  = (short*)p; p += SZ_KVP * 2;
  short* vthG = (short*)p; p += SZ_KVP * 2;
  short* vtlG = (short*)p; p += SZ_KVP * 2;
  short* wqh = (short*)p; p += W_Q * 2;
  short* wql = (short*)p; p += W_Q * 2;
  short* wkh = (short*)p; p += W_KV * 2;
  short* wkl = (short*)p; p += W_KV * 2;
  short* wvh = (short*)p; p += W_KV * 2;
  short* wvl = (short*)p; p += W_KV * 2;
  short* woh = (short*)p; p += W_Q * 2;
  short* wol = (short*)p; p += W_Q * 2;
  short* wfh = (short*)p; p += W_FC * 2;
  short* wfl = (short*)p; p += W_FC * 2;
  short* wph = (short*)p; p += W_FC * 2;
  short* wpl = (short*)p; p += W_FC * 2;
  short* hwh = (short*)p; p += W_HD * 2;
  short* hwl = (short*)p; p += W_HD * 2;

  // ---- weight conversion (memory-bound) ----
  auto wc = [&](const float* s, short* h, short* l2, long n) {
    long n8 = n / 8;
    int blocks = (int)((n8 + 255) / 256);
    wcvt_kernel<<<blocks, 256, 0, stream>>>(s, h, l2, n8);
  };
  wc(Wq, wqh, wql, W_Q);
  wc(Wk, wkh, wkl, W_KV);
  wc(Wv, wvh, wvl, W_KV);
  wc(Wo, woh, wol, W_Q);
  wc(Wfc, wfh, wfl, W_FC);
  wc(Wp, wph, wpl, W_FC);
  wc(head_w, hwh, hwl, W_HD);

  embed_kernel<<<NTOK, 256, 0, stream>>>(ids, embed_w, big_w, big_proj,
                                         big_scale, ve_w, ve_proj, ve_scale,
                                         raw_x, vemb);
  smear_kernel<<<(int)(SZ_X / 256), 256, 0, stream>>>(raw_x, smear_gate, x, x0);

  for (int l = 0; l < Lc; ++l) {
    const float* mix = resid_mix + (size_t)l * 2 * Dc;
    prelayer_kernel<<<NTOK, 256, 0, stream>>>(x, x0, mix, x_in, xnh, xnl);
    // fused q,k,v projections (768 blocks)
    qkv_sb<<<dim3(NTOK / 64, 24), 256, 0, stream>>>(
        xnh, xnl, wqh + (size_t)l * Dc * Dc, wql + (size_t)l * Dc * Dc,
        wkh + (size_t)l * KVDc * Dc, wkl + (size_t)l * KVDc * Dc,
        wvh + (size_t)l * KVDc * Dc, wvl + (size_t)l * KVDc * Dc, qb, kb, vb,
        vemb, Dc);
    qkrope_kernel<<<NTOK, 256, 0, stream>>>(qb, kb, q_gain + (size_t)l * Hc);
    kvprep_kernel<<<dim3(Tc / 64, Bc * HKVc), 256, 0, stream>>>(
        kb, vb, khG, klG, vthG, vtlG);
    attn_mfma<<<dim3(Bc * HKVc, Tc / 16), 256, 0, stream>>>(
        qb, vb, khG, klG, vthG, vtlG, yh, yl);
    // out proj + residual: x = x_in + attn_scale * (y @ Wo.T)  (512 blocks)
    gemm_sb64<<<dim3(NTOK / 64, Dc / 64), 256, 0, stream>>>(
        yh, yl, woh + (size_t)l * Dc * Dc, wol + (size_t)l * Dc * Dc, x, x_in,
        attn_scale + (size_t)l * Dc, Dc, Dc, 0);
    // MLP
    rms_split_kernel<<<NTOK, 256, 0, stream>>>(x, xnh, xnl);
    gemm_sb128<<<dim3(NTOK / 128, MLPc / 128), 256, 0, stream>>>(
        xnh, xnl, wfh + (size_t)l * MLPc * Dc, wfl + (size_t)l * MLPc * Dc,
        nullptr, hh, hl, nullptr, nullptr, MLPc, Dc, 1);
    gemm_sb64<<<dim3(NTOK / 64, Dc / 64), 256, 0, stream>>>(
        hh, hl, wph + (size_t)l * Dc * MLPc, wpl + (size_t)l * Dc * MLPc, x, x,
        mlp_scale + (size_t)l * Dc, Dc, MLPc, 0);
  }

  rms_split_kernel<<<NTOK, 256, 0, stream>>>(x, xnh, xnl);
  gemm_sb128<<<dim3(NTOK / 128, (Vc + 127) / 128), 256, 0, stream>>>(
      xnh, xnl, hwh, hwl, out, nullptr, nullptr, nullptr, nullptr, Vc, Dc, 0);
}